// Round 11
// baseline (254.695 us; speedup 1.0000x reference)
//
#include <hip/hip_runtime.h>
#include <hip/hip_fp16.h>
#include <math.h>

namespace {

constexpr int NN = 100000;   // nodes
constexpr int NE = 1000000;  // edges
constexpr int D  = 64;       // feature dim

constexpr int RPB_LOG = 8;                        // rows per bucket = 256
constexpr int RPB = 1 << RPB_LOG;
constexpr int NBUK = (NN + RPB - 1) >> RPB_LOG;   // 391 buckets
constexpr int CAP = 4096;                         // bucket capacity (mean 2558, +30 sigma)
constexpr int TILE = 2048;                        // edges per bin tile
constexpr int NTILES = (NE + TILE - 1) / TILE;    // 489
constexpr int G1B = (NN / 16 + 3) / 4;            // gemm1 blocks (4 waves x 16 rows)

using ushort_t = unsigned short;
typedef __attribute__((ext_vector_type(8))) short short8;  // 8 bf16 (4 VGPRs)
typedef __attribute__((ext_vector_type(4))) float f32x4;   // MFMA 16x16 accumulator

union FragU { uint4 v; short8 s; };

// split two fp32 into packed bf16 hi parts and packed bf16 lo (residual) parts.
__device__ inline void split2(float f0, float f1, unsigned int& hi, unsigned int& lo) {
    unsigned int u0 = __float_as_uint(f0);
    unsigned int u1 = __float_as_uint(f1);
    hi = (u0 >> 16) | (u1 & 0xffff0000u);
    float l0 = f0 - __uint_as_float(u0 & 0xffff0000u);
    float l1 = f1 - __uint_as_float(u1 & 0xffff0000u);
    lo = (__float_as_uint(l0) >> 16) | (__float_as_uint(l1) & 0xffff0000u);
}

__device__ inline unsigned int packh(float a, float b) {   // 2x fp16 (RNE) packed
    union { __half2 h; unsigned int u; } cv;
    cv.h = __float22half2_rn(make_float2(a, b));
    return cv.u;
}

__device__ inline float2 h2f(unsigned int v) {
    union { unsigned int u; __half2 h; } cv;
    cv.u = v;
    return __half22float2(cv.h);
}

// Build this wave's W^T MFMA A-fragments (bf16 hi/lo) directly from W (L2-hot
// 16KB): lane l holds A[m][k], m = ft*16 + (l&15), k = kt*32 + (l>>4)*8 + j.
__device__ inline void build_wfrags(const float* __restrict__ W, int lane,
                                    FragU (&whi)[4][2], FragU (&wlo)[4][2]) {
#pragma unroll
    for (int ft = 0; ft < 4; ++ft) {
#pragma unroll
        for (int kt = 0; kt < 2; ++kt) {
            int m  = ft * 16 + (lane & 15);
            int k0 = kt * 32 + (lane >> 4) * 8;
            unsigned int hi0, lo0, hi1, lo1, hi2, lo2, hi3, lo3;
            split2(W[(k0 + 0) * 64 + m], W[(k0 + 1) * 64 + m], hi0, lo0);
            split2(W[(k0 + 2) * 64 + m], W[(k0 + 3) * 64 + m], hi1, lo1);
            split2(W[(k0 + 4) * 64 + m], W[(k0 + 5) * 64 + m], hi2, lo2);
            split2(W[(k0 + 6) * 64 + m], W[(k0 + 7) * 64 + m], hi3, lo3);
            whi[ft][kt].v = make_uint4(hi0, hi1, hi2, hi3);
            wlo[ft][kt].v = make_uint4(lo0, lo1, lo2, lo3);
        }
    }
}

// FUSED preprocessing + layer-1 GEMM (independent block roles, co-resident so
// gemm1's compute fills the issue slots the latency/atomic-bound binning
// leaves idle; same-stream dispatches would serialize them).
// Blocks [0, NTILES): bin edges into 391 fixed-capacity row-range buckets
//   (LDS-local atomics + one global atomic per (block,bucket); R7 lesson:
//   edge-scale device atomics / random 4B stores = ~70us/pass, never again).
//   Payload packed: (r & 255) << 17 | c.
// Block NTILES: W2 MFMA A-fragments -> fb (for agg_gemm).
// Blocks > NTILES: layer-1 MFMA GEMM, one wave per 16 rows:
//   tPN[c] = [fp16(x[c]@W1) | fp16(x[perm[c]]@W1)]  -- UNSCALED (dis is not
//   available yet; it gets applied per-neighbor at gather time as an fmaf
//   with a wave-uniform scalar, same VALU count). W1 frags built in-wave
//   (no dependency on the wfrag block -> no intra-grid race).
__global__ void pre_k(const int* __restrict__ rows, const int* __restrict__ cols,
                      int* __restrict__ bcount, unsigned int* __restrict__ binned, int e,
                      const float* __restrict__ W1, const float* __restrict__ W2,
                      uint4* __restrict__ fb,
                      const float* __restrict__ x, const int* __restrict__ perm,
                      ushort_t* __restrict__ tPN) {
    __shared__ int hist[NBUK];
    __shared__ int gbase[NBUK];
    __shared__ int lofs[NBUK];
    int bid = blockIdx.x;

    if (bid > NTILES) {
        // ---- layer-1 GEMM path ----
        int lane  = threadIdx.x & 63;
        int wtile = (bid - NTILES - 1) * 4 + (threadIdx.x >> 6);
        if (wtile * 16 >= NN) return;
        int node = wtile * 16 + (lane & 15);
        int kg   = lane >> 4;

        FragU whi[4][2];
        FragU wlo[4][2];
        build_wfrags(W1, lane, whi, wlo);

        const float4* xr = (const float4*)x;
        size_t rbase = (size_t)node * 16 + (size_t)(kg * 2);
        int pnode = perm[node];
        size_t pbase = (size_t)pnode * 16 + (size_t)(kg * 2);
        f32x4 accP[4];
        f32x4 accN[4];
#pragma unroll
        for (int ft = 0; ft < 4; ++ft) {
            accP[ft] = f32x4{0.f, 0.f, 0.f, 0.f};
            accN[ft] = f32x4{0.f, 0.f, 0.f, 0.f};
        }
#pragma unroll
        for (int kt = 0; kt < 2; ++kt) {
            float4 a0 = xr[rbase + kt * 8];
            float4 a1 = xr[rbase + kt * 8 + 1];
            float4 g0 = xr[pbase + kt * 8];
            float4 g1 = xr[pbase + kt * 8 + 1];
            unsigned int h0, l0, h1, l1, h2, l2, h3, l3;
            split2(a0.x, a0.y, h0, l0);
            split2(a0.z, a0.w, h1, l1);
            split2(a1.x, a1.y, h2, l2);
            split2(a1.z, a1.w, h3, l3);
            FragU xhiP, xloP;
            xhiP.v = make_uint4(h0, h1, h2, h3);
            xloP.v = make_uint4(l0, l1, l2, l3);
            split2(g0.x, g0.y, h0, l0);
            split2(g0.z, g0.w, h1, l1);
            split2(g1.x, g1.y, h2, l2);
            split2(g1.z, g1.w, h3, l3);
            FragU xhiN, xloN;
            xhiN.v = make_uint4(h0, h1, h2, h3);
            xloN.v = make_uint4(l0, l1, l2, l3);
#pragma unroll
            for (int ft = 0; ft < 4; ++ft) {
                accP[ft] = __builtin_amdgcn_mfma_f32_16x16x32_bf16(whi[ft][kt].s, xhiP.s, accP[ft], 0, 0, 0);
                accP[ft] = __builtin_amdgcn_mfma_f32_16x16x32_bf16(whi[ft][kt].s, xloP.s, accP[ft], 0, 0, 0);
                accP[ft] = __builtin_amdgcn_mfma_f32_16x16x32_bf16(wlo[ft][kt].s, xhiP.s, accP[ft], 0, 0, 0);
                accN[ft] = __builtin_amdgcn_mfma_f32_16x16x32_bf16(whi[ft][kt].s, xhiN.s, accN[ft], 0, 0, 0);
                accN[ft] = __builtin_amdgcn_mfma_f32_16x16x32_bf16(whi[ft][kt].s, xloN.s, accN[ft], 0, 0, 0);
                accN[ft] = __builtin_amdgcn_mfma_f32_16x16x32_bf16(wlo[ft][kt].s, xhiN.s, accN[ft], 0, 0, 0);
            }
        }
        int fo = kg * 4;
        ushort_t* p = tPN + (size_t)node * 128;
#pragma unroll
        for (int ft = 0; ft < 4; ++ft) {
            uint2 up = make_uint2(packh(accP[ft][0], accP[ft][1]),
                                  packh(accP[ft][2], accP[ft][3]));
            *(uint2*)(p + ft * 16 + fo) = up;
            uint2 un = make_uint2(packh(accN[ft][0], accN[ft][1]),
                                  packh(accN[ft][2], accN[ft][3]));
            *(uint2*)(p + 64 + ft * 16 + fo) = un;
        }
        return;
    }

    if (bid == NTILES) {
        // ---- W2 fragment table for agg_gemm ----
        int lane = threadIdx.x;
        if (lane < 64) {
            for (int ft = 0; ft < 4; ++ft) {
                for (int kt = 0; kt < 2; ++kt) {
                    int m  = ft * 16 + (lane & 15);
                    int k0 = kt * 32 + (lane >> 4) * 8;
                    unsigned int hi0, lo0, hi1, lo1, hi2, lo2, hi3, lo3;
                    split2(W2[(k0 + 0) * 64 + m], W2[(k0 + 1) * 64 + m], hi0, lo0);
                    split2(W2[(k0 + 2) * 64 + m], W2[(k0 + 3) * 64 + m], hi1, lo1);
                    split2(W2[(k0 + 4) * 64 + m], W2[(k0 + 5) * 64 + m], hi2, lo2);
                    split2(W2[(k0 + 6) * 64 + m], W2[(k0 + 7) * 64 + m], hi3, lo3);
                    fb[((ft * 2 + kt) * 2 + 0) * 64 + lane] = make_uint4(hi0, hi1, hi2, hi3);
                    fb[((ft * 2 + kt) * 2 + 1) * 64 + lane] = make_uint4(lo0, lo1, lo2, lo3);
                }
            }
        }
        return;
    }

    // ---- edge binning path ----
    int base = bid * TILE;
    for (int i = threadIdx.x; i < NBUK; i += blockDim.x) {
        hist[i] = 0;
        lofs[i] = 0;
    }
    __syncthreads();
    int r[8];
    int c[8];
    int bk[8];
#pragma unroll
    for (int j = 0; j < 8; ++j) {
        int i = base + j * 256 + threadIdx.x;
        if (i < e) {
            r[j] = rows[i];
            c[j] = cols[i];
            bk[j] = r[j] >> RPB_LOG;
            atomicAdd(&hist[bk[j]], 1);
        } else {
            bk[j] = -1;
        }
    }
    __syncthreads();
    for (int b = threadIdx.x; b < NBUK; b += blockDim.x) {
        int h = hist[b];
        gbase[b] = h ? atomicAdd(&bcount[b], h) : 0;
    }
    __syncthreads();
#pragma unroll
    for (int j = 0; j < 8; ++j) {
        if (bk[j] >= 0) {
            int l = gbase[bk[j]] + atomicAdd(&lofs[bk[j]], 1);
            if (l < CAP) {
                unsigned int v = ((unsigned int)(r[j] & (RPB - 1)) << 17) | (unsigned int)c[j];
                binned[(size_t)bk[j] * CAP + l] = v;
            }
        }
    }
}

// Phase B: per-bucket counting sort + per-row deg/rowstart/dis production.
// Bucket base (exclusive scan of bcount over buckets < b) computed in-block.
__global__ void bucket_sort_k(const unsigned int* __restrict__ binned,
                              const int* __restrict__ bcount,
                              int* __restrict__ scols, int* __restrict__ rowstart,
                              int* __restrict__ deg, float* __restrict__ dis) {
    __shared__ int lcur[RPB];
    __shared__ int srs[RPB];
    __shared__ int wsum[8];
    __shared__ int redpart[8];
    __shared__ int sbase;
    int b = blockIdx.x;
    int row0 = b << RPB_LOG;
    int nrows = min(RPB, NN - row0);
    int cnt = bcount[b];
    const unsigned int* src = binned + (size_t)b * CAP;
    int tid = threadIdx.x;
    int lane = tid & 63;
    int wid = tid >> 6;

    // in-block exclusive bucket base: sum of bcount[i] for i < b
    int bv = (tid < NBUK && tid < b) ? bcount[tid] : 0;
    int bs = bv;
#pragma unroll
    for (int off = 1; off < 64; off <<= 1) {
        bs += __shfl_xor(bs, off, 64);
    }
    if (lane == 0) redpart[wid] = bs;
    __syncthreads();
    if (tid == 0) {
        int t = 0;
        for (int w = 0; w < 8; ++w) t += redpart[w];
        sbase = t;
    }
    if (tid < RPB) {
        lcur[tid] = 0;
    }
    __syncthreads();
    int bb = sbase;

    for (int i = tid; i < cnt; i += blockDim.x) {
        atomicAdd(&lcur[src[i] >> 17], 1);
    }
    __syncthreads();
    int d = (tid < nrows) ? lcur[tid] : 0;
    int inc = d;
#pragma unroll
    for (int off = 1; off < 64; off <<= 1) {
        int t = __shfl_up(inc, off);
        if (lane >= off) inc += t;
    }
    if (lane == 63) wsum[wid] = inc;
    __syncthreads();
    int wpre = 0;
    for (int w = 0; w < wid; ++w) wpre += wsum[w];
    int gstart = bb + wpre + inc - d;   // global exclusive prefix
    if (tid < nrows) {
        rowstart[row0 + tid] = gstart;
        deg[row0 + tid] = d;
        dis[row0 + tid] = rsqrtf((float)(d + 1));  // +1 self-loop
    }
    __syncthreads();
    if (tid < RPB) {
        srs[tid] = gstart;
        lcur[tid] = 0;
    }
    __syncthreads();
    for (int i = tid; i < cnt; i += blockDim.x) {
        unsigned int v = src[i];
        int rl = (int)(v >> 17);
        int pos = srs[rl] + atomicAdd(&lcur[rl], 1);
        scols[pos] = (int)(v & 0x1FFFFu);
    }
}

// FUSED layer-1 aggregate + layer-2 GEMM. One block (4 waves) owns 16 rows.
// Phase 1 (gather, R2-proven structure): each wave aggregates 4 rows
// sequentially; table is UNSCALED, so each neighbor contributes
// dis[c] * t[c] via fmaf with a wave-uniform scalar dis[c] (same VALU count
// as the old add; scols/dis reads stay scalar). Self term scaled by dis[r].
// H row (post bias+PReLU) parked in LDS [half][16][68] fp32.
// Phase 2 (MFMA): waves 0,1 -> P, waves 2,3 -> N; 2 ftiles/wave; epilogue
// scales by dis[row] and writes the SCALED fp16 table tOut (dense 8B stores).
__global__ void agg_gemm_k(const ushort_t* __restrict__ tIn, ushort_t* __restrict__ tOut,
                           const float* __restrict__ dis,
                           const int* __restrict__ rowstart, const int* __restrict__ deg,
                           const int* __restrict__ scols,
                           const float* __restrict__ bias, const float* __restrict__ prelu_a,
                           const uint4* __restrict__ wf) {
    __shared__ float Hs[2][16][68];
    int tid = threadIdx.x;
    int lane = tid & 63;
    int wv = tid >> 6;                 // 0..3
    int row0 = blockIdx.x * 16;
    int hl = lane & 31;
    int half = lane >> 5;
    size_t lofs = (size_t)(half * 64 + hl * 2);
    float aPr = *prelu_a;

    for (int rr = 0; rr < 4; ++rr) {
        int r = row0 + wv * 4 + rr;
        int rs   = __builtin_amdgcn_readfirstlane(r);
        int base = __builtin_amdgcn_readfirstlane(rowstart[rs]);
        int dg   = __builtin_amdgcn_readfirstlane(deg[rs]);
        float dr = dis[rs];
        unsigned int sv = *(const unsigned int*)(tIn + (size_t)rs * 128 + lofs);
        float2 fs = h2f(sv);
        float a0 = dr * fs.x;
        float a1 = dr * fs.y;     // self-loop term (dis[rs] * t[rs])
        int j = 0;
        for (; j + 4 <= dg; j += 4) {
            int c0 = scols[base + j];
            int c1 = scols[base + j + 1];
            int c2 = scols[base + j + 2];
            int c3 = scols[base + j + 3];
            float d0 = dis[c0];
            float d1 = dis[c1];
            float d2 = dis[c2];
            float d3 = dis[c3];
            unsigned int v0 = *(const unsigned int*)(tIn + (size_t)c0 * 128 + lofs);
            unsigned int v1 = *(const unsigned int*)(tIn + (size_t)c1 * 128 + lofs);
            unsigned int v2 = *(const unsigned int*)(tIn + (size_t)c2 * 128 + lofs);
            unsigned int v3 = *(const unsigned int*)(tIn + (size_t)c3 * 128 + lofs);
            float2 f0 = h2f(v0);
            float2 f1 = h2f(v1);
            float2 f2 = h2f(v2);
            float2 f3 = h2f(v3);
            a0 = fmaf(d0, f0.x, a0);
            a1 = fmaf(d0, f0.y, a1);
            a0 = fmaf(d1, f1.x, a0);
            a1 = fmaf(d1, f1.y, a1);
            a0 = fmaf(d2, f2.x, a0);
            a1 = fmaf(d2, f2.y, a1);
            a0 = fmaf(d3, f3.x, a0);
            a1 = fmaf(d3, f3.y, a1);
        }
        for (; j < dg; ++j) {
            int c = scols[base + j];
            float dc = dis[c];
            unsigned int v = *(const unsigned int*)(tIn + (size_t)c * 128 + lofs);
            float2 f = h2f(v);
            a0 = fmaf(dc, f.x, a0);
            a1 = fmaf(dc, f.y, a1);
        }
        float2 bv = *(const float2*)(bias + 2 * hl);
        float v0 = fmaf(dr, a0, bv.x);
        float v1 = fmaf(dr, a1, bv.y);
        v0 = v0 >= 0.f ? v0 : aPr * v0;
        v1 = v1 >= 0.f ? v1 : aPr * v1;
        int rl = wv * 4 + rr;
        Hs[half][rl][2 * hl]     = v0;
        Hs[half][rl][2 * hl + 1] = v1;
    }
    __syncthreads();

    // layer-2: out[row] = dis[row] * (H[row] @ W2), per half
    int kg = lane >> 4;
    int nd = lane & 15;
    int hsel = wv >> 1;                // waves 0,1 -> P; 2,3 -> N
    int ftb = (wv & 1) * 2;            // ftiles {0,1} or {2,3}
    FragU whi[2][2];
    FragU wlo[2][2];
#pragma unroll
    for (int f2 = 0; f2 < 2; ++f2) {
#pragma unroll
        for (int kt = 0; kt < 2; ++kt) {
            whi[f2][kt].v = wf[(((ftb + f2) * 2 + kt) * 2 + 0) * 64 + lane];
            wlo[f2][kt].v = wf[(((ftb + f2) * 2 + kt) * 2 + 1) * 64 + lane];
        }
    }
    f32x4 acc[2];
    acc[0] = f32x4{0.f, 0.f, 0.f, 0.f};
    acc[1] = f32x4{0.f, 0.f, 0.f, 0.f};
#pragma unroll
    for (int kt = 0; kt < 2; ++kt) {
        float4 a0 = *(const float4*)&Hs[hsel][nd][kt * 32 + kg * 8];
        float4 a1 = *(const float4*)&Hs[hsel][nd][kt * 32 + kg * 8 + 4];
        unsigned int h0, l0, h1, l1, h2, l2, h3, l3;
        split2(a0.x, a0.y, h0, l0);
        split2(a0.z, a0.w, h1, l1);
        split2(a1.x, a1.y, h2, l2);
        split2(a1.z, a1.w, h3, l3);
        FragU xhi, xlo;
        xhi.v = make_uint4(h0, h1, h2, h3);
        xlo.v = make_uint4(l0, l1, l2, l3);
#pragma unroll
        for (int f2 = 0; f2 < 2; ++f2) {
            acc[f2] = __builtin_amdgcn_mfma_f32_16x16x32_bf16(whi[f2][kt].s, xhi.s, acc[f2], 0, 0, 0);
            acc[f2] = __builtin_amdgcn_mfma_f32_16x16x32_bf16(whi[f2][kt].s, xlo.s, acc[f2], 0, 0, 0);
            acc[f2] = __builtin_amdgcn_mfma_f32_16x16x32_bf16(wlo[f2][kt].s, xhi.s, acc[f2], 0, 0, 0);
        }
    }
    float s = dis[row0 + nd];
    ushort_t* p = tOut + (size_t)(row0 + nd) * 128 + hsel * 64;
    int fo = kg * 4;
#pragma unroll
    for (int f2 = 0; f2 < 2; ++f2) {
        uint2 u = make_uint2(packh(s * acc[f2][0], s * acc[f2][1]),
                             packh(s * acc[f2][2], s * acc[f2][3]));
        *(uint2*)(p + (ftb + f2) * 16 + fo) = u;
    }
}

// Dual gather-aggregate over the interleaved SCALED fp16 table (final layer).
// One wave per row; lanes 0-31 = P half, 32-63 = N half; 2 feats/lane.
// outX[r] = dis[r]*(sum_j tX[c_j] + tX[r]) + b
__global__ void agg_dual_k(const ushort_t* __restrict__ tPN,
                           float* __restrict__ dstP, float* __restrict__ dstN,
                           const float* __restrict__ dis,
                           const int* __restrict__ rowstart, const int* __restrict__ deg,
                           const int* __restrict__ scols,
                           const float* __restrict__ bias, int n) {
    int lane = threadIdx.x & 63;
    int hl = lane & 31;
    int half = lane >> 5;
    int r = blockIdx.x * (blockDim.x >> 6) + (threadIdx.x >> 6);
    if (r >= n) return;
    int rs   = __builtin_amdgcn_readfirstlane(r);
    int base = __builtin_amdgcn_readfirstlane(rowstart[rs]);
    int dg   = __builtin_amdgcn_readfirstlane(deg[rs]);
    float dr = dis[rs];
    size_t lofs = (size_t)(half * 64 + hl * 2);
    unsigned int sv = *(const unsigned int*)(tPN + (size_t)rs * 128 + lofs);
    float2 fs = h2f(sv);
    float a0 = fs.x;
    float a1 = fs.y;     // self-loop term
    int j = 0;
    for (; j + 4 <= dg; j += 4) {
        int c0 = scols[base + j];
        int c1 = scols[base + j + 1];
        int c2 = scols[base + j + 2];
        int c3 = scols[base + j + 3];
        unsigned int v0 = *(const unsigned int*)(tPN + (size_t)c0 * 128 + lofs);
        unsigned int v1 = *(const unsigned int*)(tPN + (size_t)c1 * 128 + lofs);
        unsigned int v2 = *(const unsigned int*)(tPN + (size_t)c2 * 128 + lofs);
        unsigned int v3 = *(const unsigned int*)(tPN + (size_t)c3 * 128 + lofs);
        float2 f0 = h2f(v0);
        float2 f1 = h2f(v1);
        float2 f2 = h2f(v2);
        float2 f3 = h2f(v3);
        a0 += f0.x + f1.x + f2.x + f3.x;
        a1 += f0.y + f1.y + f2.y + f3.y;
    }
    for (; j < dg; ++j) {
        int c = scols[base + j];
        unsigned int v = *(const unsigned int*)(tPN + (size_t)c * 128 + lofs);
        float2 f = h2f(v);
        a0 += f.x;
        a1 += f.y;
    }
    float2 bv = *(const float2*)(bias + 2 * hl);
    float v0 = fmaf(dr, a0, bv.x);
    float v1 = fmaf(dr, a1, bv.y);
    float* dst = half ? dstN : dstP;
    *(float2*)(dst + (size_t)rs * D + 2 * hl) = float2{v0, v1};
}

// Summary partials: 512 blocks x 256 thr. 4-acc ILP on the loads (R8 lesson:
// serial `s += load` = 1 load/~590cy). Per-block LDS reduce -> ONE 64-lane
// atomicAdd per BLOCK (R9 lesson: wave-granular atomics on the same 4 cache
// lines serialize at the cross-XCD far point; 512 block atomics = ~1us).
__global__ void summary_partial_k(const float* __restrict__ pos, float* __restrict__ acc, int n) {
    __shared__ float red[4][64];
    int lane = threadIdx.x & 63;
    int wv = threadIdx.x >> 6;
    int wave = (blockIdx.x * blockDim.x + threadIdx.x) >> 6;
    int nw = (gridDim.x * blockDim.x) >> 6;
    float s0 = 0.f, s1 = 0.f, s2 = 0.f, s3 = 0.f;
    int r = wave;
    for (; r + 3 * nw < n; r += 4 * nw) {
        s0 += pos[(size_t)r * D + lane];
        s1 += pos[(size_t)(r + nw) * D + lane];
        s2 += pos[(size_t)(r + 2 * nw) * D + lane];
        s3 += pos[(size_t)(r + 3 * nw) * D + lane];
    }
    for (; r < n; r += nw) {
        s0 += pos[(size_t)r * D + lane];
    }
    red[wv][lane] = (s0 + s1) + (s2 + s3);
    __syncthreads();
    if (wv == 0) {
        float t = (red[0][lane] + red[1][lane]) + (red[2][lane] + red[3][lane]);
        atomicAdd(&acc[lane], t);
    }
}

__global__ void summary_final_k(const float* __restrict__ acc, float* __restrict__ out, int n) {
    int f = threadIdx.x;
    if (f < D) {
        float m = acc[f] / (float)n;
        out[f] = 1.f / (1.f + expf(-m));
    }
}

} // namespace

extern "C" void kernel_launch(void* const* d_in, const int* in_sizes, int n_in,
                              void* d_out, int out_size, void* d_ws, size_t ws_size,
                              hipStream_t stream) {
    (void)in_sizes; (void)n_in; (void)out_size; (void)ws_size;
    const float* x       = (const float*)d_in[0];
    const int*   ei      = (const int*)  d_in[1];
    const int*   perm    = (const int*)  d_in[2];
    const float* W1      = (const float*)d_in[3];
    const float* b1      = (const float*)d_in[4];
    const float* prelu_a = (const float*)d_in[5];
    const float* W2      = (const float*)d_in[6];
    const float* b2      = (const float*)d_in[7];

    float* outP = (float*)d_out;
    float* outN = outP + (size_t)NN * D;
    float* outS = outN + (size_t)NN * D;

    const int* erows = ei;
    const int* ecols = ei + NE;

    char* ws = (char*)d_ws;
    size_t off = 0;
    auto alloc = [&](size_t bytes) {
        void* p = ws + off;
        off = (off + bytes + 255) & ~(size_t)255;
        return p;
    };
    int*      deg      = (int*)     alloc((size_t)NN * 4);
    float*    dis      = (float*)   alloc((size_t)NN * 4);
    int*      rowstart = (int*)     alloc((size_t)NN * 4);
    int*      bcount   = (int*)     alloc((size_t)NBUK * 4);   // } one memset span
    float*    acc      = (float*)   alloc((size_t)D * 4);      // } (bcount..acc)
    unsigned int* binned = (unsigned int*)alloc((size_t)NBUK * CAP * 4);  // 6.4 MB
    int*      scols    = (int*)     alloc((size_t)NE * 4);
    ushort_t* tPN      = (ushort_t*)alloc((size_t)NN * 128 * 2);   // layer-1 fp16 table (UNSCALED), 25.6 MB
    ushort_t* tPN2     = (ushort_t*)alloc((size_t)NN * 128 * 2);   // layer-2 fp16 table (scaled), 25.6 MB
    uint4*    wfrag    = (uint4*)   alloc((size_t)1024 * 16);      // W2 bf16 hi/lo frags, 16 KB
    // ~65 MB total

    // one memset covers bcount (incl. alignment pad) + acc
    hipMemsetAsync(bcount, 0, (size_t)((char*)acc - (char*)bcount) + (size_t)D * 4, stream);

    // fused preprocessing + layer-1 GEMM (bin blocks + W2-frag block + gemm blocks)
    pre_k<<<NTILES + 1 + G1B, 256, 0, stream>>>(erows, ecols, bcount, binned, NE,
                                                W1, W2, wfrag, x, perm, tPN);
    bucket_sort_k<<<NBUK, 512, 0, stream>>>(binned, bcount, scols, rowstart, deg, dis);

    // fused layer-1 aggregate (per-neighbor dis fmaf, +b1, PReLU) + layer-2 GEMM
    agg_gemm_k<<<NN / 16, 256, 0, stream>>>(tPN, tPN2, dis, rowstart, deg, scols,
                                            b1, prelu_a, wfrag);

    // final aggregate (+b2) -> outputs
    agg_dual_k<<<(NN + 3) / 4, 256, 0, stream>>>(tPN2, outP, outN, dis, rowstart, deg,
                                                 scols, b2, NN);

    // summary = sigmoid(mean(positive, axis=0))
    summary_partial_k<<<512, 256, 0, stream>>>(outP, acc, NN);
    summary_final_k<<<1, 64, 0, stream>>>(acc, outS, NN);
}

// Round 12
// 241.274 us; speedup vs baseline: 1.0556x; 1.0556x over previous
//
#include <hip/hip_runtime.h>
#include <hip/hip_fp16.h>
#include <math.h>

namespace {

constexpr int NN = 100000;   // nodes
constexpr int NE = 1000000;  // edges
constexpr int D  = 64;       // feature dim

constexpr int RPB_LOG = 8;                        // rows per bucket = 256
constexpr int RPB = 1 << RPB_LOG;
constexpr int NBUK = (NN + RPB - 1) >> RPB_LOG;   // 391 buckets
constexpr int CAP = 4096;                         // bucket capacity (mean 2558, +30 sigma)
constexpr int TILE = 8192;                        // edges per bin tile (R12: 4x bigger ->
                                                  //  4x fewer allocator atomics, ~84B chunks)
constexpr int NTILES = (NE + TILE - 1) / TILE;    // 123
constexpr int EPT = TILE / 512;                   // 16 edges per thread
constexpr int G1B = (NN / 16 + 7) / 8;            // gemm1 blocks (8 waves x 16 rows)

using ushort_t = unsigned short;
typedef __attribute__((ext_vector_type(8))) short short8;  // 8 bf16 (4 VGPRs)
typedef __attribute__((ext_vector_type(4))) float f32x4;   // MFMA 16x16 accumulator

union FragU { uint4 v; short8 s; };

// split two fp32 into packed bf16 hi parts and packed bf16 lo (residual) parts.
__device__ inline void split2(float f0, float f1, unsigned int& hi, unsigned int& lo) {
    unsigned int u0 = __float_as_uint(f0);
    unsigned int u1 = __float_as_uint(f1);
    hi = (u0 >> 16) | (u1 & 0xffff0000u);
    float l0 = f0 - __uint_as_float(u0 & 0xffff0000u);
    float l1 = f1 - __uint_as_float(u1 & 0xffff0000u);
    lo = (__float_as_uint(l0) >> 16) | (__float_as_uint(l1) & 0xffff0000u);
}

__device__ inline unsigned int packh(float a, float b) {   // 2x fp16 (RNE) packed
    union { __half2 h; unsigned int u; } cv;
    cv.h = __float22half2_rn(make_float2(a, b));
    return cv.u;
}

__device__ inline float2 h2f(unsigned int v) {
    union { unsigned int u; __half2 h; } cv;
    cv.u = v;
    return __half22float2(cv.h);
}

// Build this wave's W^T MFMA A-fragments (bf16 hi/lo) directly from W (L2-hot
// 16KB): lane l holds A[m][k], m = ft*16 + (l&15), k = kt*32 + (l>>4)*8 + j.
__device__ inline void build_wfrags(const float* __restrict__ W, int lane,
                                    FragU (&whi)[4][2], FragU (&wlo)[4][2]) {
#pragma unroll
    for (int ft = 0; ft < 4; ++ft) {
#pragma unroll
        for (int kt = 0; kt < 2; ++kt) {
            int m  = ft * 16 + (lane & 15);
            int k0 = kt * 32 + (lane >> 4) * 8;
            unsigned int hi0, lo0, hi1, lo1, hi2, lo2, hi3, lo3;
            split2(W[(k0 + 0) * 64 + m], W[(k0 + 1) * 64 + m], hi0, lo0);
            split2(W[(k0 + 2) * 64 + m], W[(k0 + 3) * 64 + m], hi1, lo1);
            split2(W[(k0 + 4) * 64 + m], W[(k0 + 5) * 64 + m], hi2, lo2);
            split2(W[(k0 + 6) * 64 + m], W[(k0 + 7) * 64 + m], hi3, lo3);
            whi[ft][kt].v = make_uint4(hi0, hi1, hi2, hi3);
            wlo[ft][kt].v = make_uint4(lo0, lo1, lo2, lo3);
        }
    }
}

// FUSED preprocessing + layer-1 GEMM (independent block roles, co-resident so
// gemm1's compute fills the issue slots the latency/atomic-bound binning
// leaves idle). 512-thread blocks.
// Blocks [0, NTILES): bin 8192 edges each into 391 fixed-capacity row-range
//   buckets (LDS-local atomics; ONE global allocator atomic per
//   (block,bucket) -- 48K total; ~84B dense chunks cut RFO write
//   amplification ~3x vs TILE=2048's 21B chunks. R7 lesson: edge-scale
//   device atomics / random 4B stores = ~70us/pass, never again).
//   Payload packed: (r & 255) << 17 | c.
// Block NTILES: W2 MFMA A-fragments -> fb (for agg_gemm).
// Blocks > NTILES: layer-1 MFMA GEMM, 8 waves x 16 rows per block:
//   tPN[c] = [fp16(x[c]@W1) | fp16(x[perm[c]]@W1)]  -- UNSCALED (dis not yet
//   available; applied per-neighbor at gather time as fmaf with wave-uniform
//   scalar). W1 frags built in-wave (no cross-block dependency).
__global__ void pre_k(const int* __restrict__ rows, const int* __restrict__ cols,
                      int* __restrict__ bcount, unsigned int* __restrict__ binned, int e,
                      const float* __restrict__ W1, const float* __restrict__ W2,
                      uint4* __restrict__ fb,
                      const float* __restrict__ x, const int* __restrict__ perm,
                      ushort_t* __restrict__ tPN) {
    __shared__ int hist[NBUK];
    __shared__ int gbase[NBUK];
    __shared__ int lofs[NBUK];
    int bid = blockIdx.x;

    if (bid > NTILES) {
        // ---- layer-1 GEMM path ----
        int lane  = threadIdx.x & 63;
        int wtile = (bid - NTILES - 1) * 8 + (threadIdx.x >> 6);
        if (wtile * 16 >= NN) return;
        int node = wtile * 16 + (lane & 15);
        int kg   = lane >> 4;

        FragU whi[4][2];
        FragU wlo[4][2];
        build_wfrags(W1, lane, whi, wlo);

        const float4* xr = (const float4*)x;
        size_t rbase = (size_t)node * 16 + (size_t)(kg * 2);
        int pnode = perm[node];
        size_t pbase = (size_t)pnode * 16 + (size_t)(kg * 2);
        f32x4 accP[4];
        f32x4 accN[4];
#pragma unroll
        for (int ft = 0; ft < 4; ++ft) {
            accP[ft] = f32x4{0.f, 0.f, 0.f, 0.f};
            accN[ft] = f32x4{0.f, 0.f, 0.f, 0.f};
        }
#pragma unroll
        for (int kt = 0; kt < 2; ++kt) {
            float4 a0 = xr[rbase + kt * 8];
            float4 a1 = xr[rbase + kt * 8 + 1];
            float4 g0 = xr[pbase + kt * 8];
            float4 g1 = xr[pbase + kt * 8 + 1];
            unsigned int h0, l0, h1, l1, h2, l2, h3, l3;
            split2(a0.x, a0.y, h0, l0);
            split2(a0.z, a0.w, h1, l1);
            split2(a1.x, a1.y, h2, l2);
            split2(a1.z, a1.w, h3, l3);
            FragU xhiP, xloP;
            xhiP.v = make_uint4(h0, h1, h2, h3);
            xloP.v = make_uint4(l0, l1, l2, l3);
            split2(g0.x, g0.y, h0, l0);
            split2(g0.z, g0.w, h1, l1);
            split2(g1.x, g1.y, h2, l2);
            split2(g1.z, g1.w, h3, l3);
            FragU xhiN, xloN;
            xhiN.v = make_uint4(h0, h1, h2, h3);
            xloN.v = make_uint4(l0, l1, l2, l3);
#pragma unroll
            for (int ft = 0; ft < 4; ++ft) {
                accP[ft] = __builtin_amdgcn_mfma_f32_16x16x32_bf16(whi[ft][kt].s, xhiP.s, accP[ft], 0, 0, 0);
                accP[ft] = __builtin_amdgcn_mfma_f32_16x16x32_bf16(whi[ft][kt].s, xloP.s, accP[ft], 0, 0, 0);
                accP[ft] = __builtin_amdgcn_mfma_f32_16x16x32_bf16(wlo[ft][kt].s, xhiP.s, accP[ft], 0, 0, 0);
                accN[ft] = __builtin_amdgcn_mfma_f32_16x16x32_bf16(whi[ft][kt].s, xhiN.s, accN[ft], 0, 0, 0);
                accN[ft] = __builtin_amdgcn_mfma_f32_16x16x32_bf16(whi[ft][kt].s, xloN.s, accN[ft], 0, 0, 0);
                accN[ft] = __builtin_amdgcn_mfma_f32_16x16x32_bf16(wlo[ft][kt].s, xhiN.s, accN[ft], 0, 0, 0);
            }
        }
        int fo = kg * 4;
        ushort_t* p = tPN + (size_t)node * 128;
#pragma unroll
        for (int ft = 0; ft < 4; ++ft) {
            uint2 up = make_uint2(packh(accP[ft][0], accP[ft][1]),
                                  packh(accP[ft][2], accP[ft][3]));
            *(uint2*)(p + ft * 16 + fo) = up;
            uint2 un = make_uint2(packh(accN[ft][0], accN[ft][1]),
                                  packh(accN[ft][2], accN[ft][3]));
            *(uint2*)(p + 64 + ft * 16 + fo) = un;
        }
        return;
    }

    if (bid == NTILES) {
        // ---- W2 fragment table for agg_gemm ----
        int lane = threadIdx.x;
        if (lane < 64) {
            for (int ft = 0; ft < 4; ++ft) {
                for (int kt = 0; kt < 2; ++kt) {
                    int m  = ft * 16 + (lane & 15);
                    int k0 = kt * 32 + (lane >> 4) * 8;
                    unsigned int hi0, lo0, hi1, lo1, hi2, lo2, hi3, lo3;
                    split2(W2[(k0 + 0) * 64 + m], W2[(k0 + 1) * 64 + m], hi0, lo0);
                    split2(W2[(k0 + 2) * 64 + m], W2[(k0 + 3) * 64 + m], hi1, lo1);
                    split2(W2[(k0 + 4) * 64 + m], W2[(k0 + 5) * 64 + m], hi2, lo2);
                    split2(W2[(k0 + 6) * 64 + m], W2[(k0 + 7) * 64 + m], hi3, lo3);
                    fb[((ft * 2 + kt) * 2 + 0) * 64 + lane] = make_uint4(hi0, hi1, hi2, hi3);
                    fb[((ft * 2 + kt) * 2 + 1) * 64 + lane] = make_uint4(lo0, lo1, lo2, lo3);
                }
            }
        }
        return;
    }

    // ---- edge binning path (512 thr, 16 edges/thread) ----
    int base = bid * TILE;
    for (int i = threadIdx.x; i < NBUK; i += blockDim.x) {
        hist[i] = 0;
        lofs[i] = 0;
    }
    __syncthreads();
    int r[EPT];
    int c[EPT];
    int bk[EPT];
#pragma unroll
    for (int j = 0; j < EPT; ++j) {
        int i = base + j * 512 + (int)threadIdx.x;
        if (i < e) {
            r[j] = rows[i];
            c[j] = cols[i];
            bk[j] = r[j] >> RPB_LOG;
            atomicAdd(&hist[bk[j]], 1);
        } else {
            bk[j] = -1;
        }
    }
    __syncthreads();
    for (int b = threadIdx.x; b < NBUK; b += blockDim.x) {
        int h = hist[b];
        gbase[b] = h ? atomicAdd(&bcount[b], h) : 0;
    }
    __syncthreads();
#pragma unroll
    for (int j = 0; j < EPT; ++j) {
        if (bk[j] >= 0) {
            int l = gbase[bk[j]] + atomicAdd(&lofs[bk[j]], 1);
            if (l < CAP) {
                unsigned int v = ((unsigned int)(r[j] & (RPB - 1)) << 17) | (unsigned int)c[j];
                binned[(size_t)bk[j] * CAP + l] = v;
            }
        }
    }
}

// Phase B: per-bucket counting sort + per-row deg/rowstart/dis production.
// Bucket base (exclusive scan of bcount over buckets < b) computed in-block.
__global__ void bucket_sort_k(const unsigned int* __restrict__ binned,
                              const int* __restrict__ bcount,
                              int* __restrict__ scols, int* __restrict__ rowstart,
                              int* __restrict__ deg, float* __restrict__ dis) {
    __shared__ int lcur[RPB];
    __shared__ int srs[RPB];
    __shared__ int wsum[8];
    __shared__ int redpart[8];
    __shared__ int sbase;
    int b = blockIdx.x;
    int row0 = b << RPB_LOG;
    int nrows = min(RPB, NN - row0);
    int cnt = bcount[b];
    const unsigned int* src = binned + (size_t)b * CAP;
    int tid = threadIdx.x;
    int lane = tid & 63;
    int wid = tid >> 6;

    // in-block exclusive bucket base: sum of bcount[i] for i < b
    int bv = (tid < NBUK && tid < b) ? bcount[tid] : 0;
    int bs = bv;
#pragma unroll
    for (int off = 1; off < 64; off <<= 1) {
        bs += __shfl_xor(bs, off, 64);
    }
    if (lane == 0) redpart[wid] = bs;
    __syncthreads();
    if (tid == 0) {
        int t = 0;
        for (int w = 0; w < 8; ++w) t += redpart[w];
        sbase = t;
    }
    if (tid < RPB) {
        lcur[tid] = 0;
    }
    __syncthreads();
    int bb = sbase;

    for (int i = tid; i < cnt; i += blockDim.x) {
        atomicAdd(&lcur[src[i] >> 17], 1);
    }
    __syncthreads();
    int d = (tid < nrows) ? lcur[tid] : 0;
    int inc = d;
#pragma unroll
    for (int off = 1; off < 64; off <<= 1) {
        int t = __shfl_up(inc, off);
        if (lane >= off) inc += t;
    }
    if (lane == 63) wsum[wid] = inc;
    __syncthreads();
    int wpre = 0;
    for (int w = 0; w < wid; ++w) wpre += wsum[w];
    int gstart = bb + wpre + inc - d;   // global exclusive prefix
    if (tid < nrows) {
        rowstart[row0 + tid] = gstart;
        deg[row0 + tid] = d;
        dis[row0 + tid] = rsqrtf((float)(d + 1));  // +1 self-loop
    }
    __syncthreads();
    if (tid < RPB) {
        srs[tid] = gstart;
        lcur[tid] = 0;
    }
    __syncthreads();
    for (int i = tid; i < cnt; i += blockDim.x) {
        unsigned int v = src[i];
        int rl = (int)(v >> 17);
        int pos = srs[rl] + atomicAdd(&lcur[rl], 1);
        scols[pos] = (int)(v & 0x1FFFFu);
    }
}

// FUSED layer-1 aggregate + layer-2 GEMM. One block (4 waves) owns 16 rows.
// Phase 1 (gather, R2-proven structure): each wave aggregates 4 rows
// sequentially; table is UNSCALED, so each neighbor contributes
// dis[c] * t[c] via fmaf with a wave-uniform scalar dis[c]. Self term
// scaled by dis[r]. H row (post bias+PReLU) parked in LDS [half][16][68].
// Phase 2 (MFMA): waves 0,1 -> P, waves 2,3 -> N; 2 ftiles/wave; epilogue
// scales by dis[row] and writes the SCALED fp16 table tOut (dense 8B stores).
__global__ void agg_gemm_k(const ushort_t* __restrict__ tIn, ushort_t* __restrict__ tOut,
                           const float* __restrict__ dis,
                           const int* __restrict__ rowstart, const int* __restrict__ deg,
                           const int* __restrict__ scols,
                           const float* __restrict__ bias, const float* __restrict__ prelu_a,
                           const uint4* __restrict__ wf) {
    __shared__ float Hs[2][16][68];
    int tid = threadIdx.x;
    int lane = tid & 63;
    int wv = tid >> 6;                 // 0..3
    int row0 = blockIdx.x * 16;
    int hl = lane & 31;
    int half = lane >> 5;
    size_t lofs = (size_t)(half * 64 + hl * 2);
    float aPr = *prelu_a;

    for (int rr = 0; rr < 4; ++rr) {
        int r = row0 + wv * 4 + rr;
        int rs   = __builtin_amdgcn_readfirstlane(r);
        int base = __builtin_amdgcn_readfirstlane(rowstart[rs]);
        int dg   = __builtin_amdgcn_readfirstlane(deg[rs]);
        float dr = dis[rs];
        unsigned int sv = *(const unsigned int*)(tIn + (size_t)rs * 128 + lofs);
        float2 fs = h2f(sv);
        float a0 = dr * fs.x;
        float a1 = dr * fs.y;     // self-loop term (dis[rs] * t[rs])
        int j = 0;
        for (; j + 4 <= dg; j += 4) {
            int c0 = scols[base + j];
            int c1 = scols[base + j + 1];
            int c2 = scols[base + j + 2];
            int c3 = scols[base + j + 3];
            float d0 = dis[c0];
            float d1 = dis[c1];
            float d2 = dis[c2];
            float d3 = dis[c3];
            unsigned int v0 = *(const unsigned int*)(tIn + (size_t)c0 * 128 + lofs);
            unsigned int v1 = *(const unsigned int*)(tIn + (size_t)c1 * 128 + lofs);
            unsigned int v2 = *(const unsigned int*)(tIn + (size_t)c2 * 128 + lofs);
            unsigned int v3 = *(const unsigned int*)(tIn + (size_t)c3 * 128 + lofs);
            float2 f0 = h2f(v0);
            float2 f1 = h2f(v1);
            float2 f2 = h2f(v2);
            float2 f3 = h2f(v3);
            a0 = fmaf(d0, f0.x, a0);
            a1 = fmaf(d0, f0.y, a1);
            a0 = fmaf(d1, f1.x, a0);
            a1 = fmaf(d1, f1.y, a1);
            a0 = fmaf(d2, f2.x, a0);
            a1 = fmaf(d2, f2.y, a1);
            a0 = fmaf(d3, f3.x, a0);
            a1 = fmaf(d3, f3.y, a1);
        }
        for (; j < dg; ++j) {
            int c = scols[base + j];
            float dc = dis[c];
            unsigned int v = *(const unsigned int*)(tIn + (size_t)c * 128 + lofs);
            float2 f = h2f(v);
            a0 = fmaf(dc, f.x, a0);
            a1 = fmaf(dc, f.y, a1);
        }
        float2 bv = *(const float2*)(bias + 2 * hl);
        float v0 = fmaf(dr, a0, bv.x);
        float v1 = fmaf(dr, a1, bv.y);
        v0 = v0 >= 0.f ? v0 : aPr * v0;
        v1 = v1 >= 0.f ? v1 : aPr * v1;
        int rl = wv * 4 + rr;
        Hs[half][rl][2 * hl]     = v0;
        Hs[half][rl][2 * hl + 1] = v1;
    }
    __syncthreads();

    // layer-2: out[row] = dis[row] * (H[row] @ W2), per half
    int kg = lane >> 4;
    int nd = lane & 15;
    int hsel = wv >> 1;                // waves 0,1 -> P; 2,3 -> N
    int ftb = (wv & 1) * 2;            // ftiles {0,1} or {2,3}
    FragU whi[2][2];
    FragU wlo[2][2];
#pragma unroll
    for (int f2 = 0; f2 < 2; ++f2) {
#pragma unroll
        for (int kt = 0; kt < 2; ++kt) {
            whi[f2][kt].v = wf[(((ftb + f2) * 2 + kt) * 2 + 0) * 64 + lane];
            wlo[f2][kt].v = wf[(((ftb + f2) * 2 + kt) * 2 + 1) * 64 + lane];
        }
    }
    f32x4 acc[2];
    acc[0] = f32x4{0.f, 0.f, 0.f, 0.f};
    acc[1] = f32x4{0.f, 0.f, 0.f, 0.f};
#pragma unroll
    for (int kt = 0; kt < 2; ++kt) {
        float4 a0 = *(const float4*)&Hs[hsel][nd][kt * 32 + kg * 8];
        float4 a1 = *(const float4*)&Hs[hsel][nd][kt * 32 + kg * 8 + 4];
        unsigned int h0, l0, h1, l1, h2, l2, h3, l3;
        split2(a0.x, a0.y, h0, l0);
        split2(a0.z, a0.w, h1, l1);
        split2(a1.x, a1.y, h2, l2);
        split2(a1.z, a1.w, h3, l3);
        FragU xhi, xlo;
        xhi.v = make_uint4(h0, h1, h2, h3);
        xlo.v = make_uint4(l0, l1, l2, l3);
#pragma unroll
        for (int f2 = 0; f2 < 2; ++f2) {
            acc[f2] = __builtin_amdgcn_mfma_f32_16x16x32_bf16(whi[f2][kt].s, xhi.s, acc[f2], 0, 0, 0);
            acc[f2] = __builtin_amdgcn_mfma_f32_16x16x32_bf16(whi[f2][kt].s, xlo.s, acc[f2], 0, 0, 0);
            acc[f2] = __builtin_amdgcn_mfma_f32_16x16x32_bf16(wlo[f2][kt].s, xhi.s, acc[f2], 0, 0, 0);
        }
    }
    float s = dis[row0 + nd];
    ushort_t* p = tOut + (size_t)(row0 + nd) * 128 + hsel * 64;
    int fo = kg * 4;
#pragma unroll
    for (int f2 = 0; f2 < 2; ++f2) {
        uint2 u = make_uint2(packh(s * acc[f2][0], s * acc[f2][1]),
                             packh(s * acc[f2][2], s * acc[f2][3]));
        *(uint2*)(p + (ftb + f2) * 16 + fo) = u;
    }
}

// Dual gather-aggregate over the interleaved SCALED fp16 table (final layer).
// One wave per row; lanes 0-31 = P half, 32-63 = N half; 2 feats/lane.
// outX[r] = dis[r]*(sum_j tX[c_j] + tX[r]) + b
__global__ void agg_dual_k(const ushort_t* __restrict__ tPN,
                           float* __restrict__ dstP, float* __restrict__ dstN,
                           const float* __restrict__ dis,
                           const int* __restrict__ rowstart, const int* __restrict__ deg,
                           const int* __restrict__ scols,
                           const float* __restrict__ bias, int n) {
    int lane = threadIdx.x & 63;
    int hl = lane & 31;
    int half = lane >> 5;
    int r = blockIdx.x * (blockDim.x >> 6) + (threadIdx.x >> 6);
    if (r >= n) return;
    int rs   = __builtin_amdgcn_readfirstlane(r);
    int base = __builtin_amdgcn_readfirstlane(rowstart[rs]);
    int dg   = __builtin_amdgcn_readfirstlane(deg[rs]);
    float dr = dis[rs];
    size_t lofs = (size_t)(half * 64 + hl * 2);
    unsigned int sv = *(const unsigned int*)(tPN + (size_t)rs * 128 + lofs);
    float2 fs = h2f(sv);
    float a0 = fs.x;
    float a1 = fs.y;     // self-loop term
    int j = 0;
    for (; j + 4 <= dg; j += 4) {
        int c0 = scols[base + j];
        int c1 = scols[base + j + 1];
        int c2 = scols[base + j + 2];
        int c3 = scols[base + j + 3];
        unsigned int v0 = *(const unsigned int*)(tPN + (size_t)c0 * 128 + lofs);
        unsigned int v1 = *(const unsigned int*)(tPN + (size_t)c1 * 128 + lofs);
        unsigned int v2 = *(const unsigned int*)(tPN + (size_t)c2 * 128 + lofs);
        unsigned int v3 = *(const unsigned int*)(tPN + (size_t)c3 * 128 + lofs);
        float2 f0 = h2f(v0);
        float2 f1 = h2f(v1);
        float2 f2 = h2f(v2);
        float2 f3 = h2f(v3);
        a0 += f0.x + f1.x + f2.x + f3.x;
        a1 += f0.y + f1.y + f2.y + f3.y;
    }
    for (; j < dg; ++j) {
        int c = scols[base + j];
        unsigned int v = *(const unsigned int*)(tPN + (size_t)c * 128 + lofs);
        float2 f = h2f(v);
        a0 += f.x;
        a1 += f.y;
    }
    float2 bv = *(const float2*)(bias + 2 * hl);
    float v0 = fmaf(dr, a0, bv.x);
    float v1 = fmaf(dr, a1, bv.y);
    float* dst = half ? dstN : dstP;
    *(float2*)(dst + (size_t)rs * D + 2 * hl) = float2{v0, v1};
}

// Summary partials: 512 blocks x 256 thr. 4-acc ILP on the loads (R8 lesson:
// serial `s += load` = 1 load/~590cy). Per-block LDS reduce -> ONE 64-lane
// atomicAdd per BLOCK (R9 lesson: wave-granular atomics on the same 4 cache
// lines serialize at the cross-XCD far point; 512 block atomics = ~1us).
__global__ void summary_partial_k(const float* __restrict__ pos, float* __restrict__ acc, int n) {
    __shared__ float red[4][64];
    int lane = threadIdx.x & 63;
    int wv = threadIdx.x >> 6;
    int wave = (blockIdx.x * blockDim.x + threadIdx.x) >> 6;
    int nw = (gridDim.x * blockDim.x) >> 6;
    float s0 = 0.f, s1 = 0.f, s2 = 0.f, s3 = 0.f;
    int r = wave;
    for (; r + 3 * nw < n; r += 4 * nw) {
        s0 += pos[(size_t)r * D + lane];
        s1 += pos[(size_t)(r + nw) * D + lane];
        s2 += pos[(size_t)(r + 2 * nw) * D + lane];
        s3 += pos[(size_t)(r + 3 * nw) * D + lane];
    }
    for (; r < n; r += nw) {
        s0 += pos[(size_t)r * D + lane];
    }
    red[wv][lane] = (s0 + s1) + (s2 + s3);
    __syncthreads();
    if (wv == 0) {
        float t = (red[0][lane] + red[1][lane]) + (red[2][lane] + red[3][lane]);
        atomicAdd(&acc[lane], t);
    }
}

__global__ void summary_final_k(const float* __restrict__ acc, float* __restrict__ out, int n) {
    int f = threadIdx.x;
    if (f < D) {
        float m = acc[f] / (float)n;
        out[f] = 1.f / (1.f + expf(-m));
    }
}

} // namespace

extern "C" void kernel_launch(void* const* d_in, const int* in_sizes, int n_in,
                              void* d_out, int out_size, void* d_ws, size_t ws_size,
                              hipStream_t stream) {
    (void)in_sizes; (void)n_in; (void)out_size; (void)ws_size;
    const float* x       = (const float*)d_in[0];
    const int*   ei      = (const int*)  d_in[1];
    const int*   perm    = (const int*)  d_in[2];
    const float* W1      = (const float*)d_in[3];
    const float* b1      = (const float*)d_in[4];
    const float* prelu_a = (const float*)d_in[5];
    const float* W2      = (const float*)d_in[6];
    const float* b2      = (const float*)d_in[7];

    float* outP = (float*)d_out;
    float* outN = outP + (size_t)NN * D;
    float* outS = outN + (size_t)NN * D;

    const int* erows = ei;
    const int* ecols = ei + NE;

    char* ws = (char*)d_ws;
    size_t off = 0;
    auto alloc = [&](size_t bytes) {
        void* p = ws + off;
        off = (off + bytes + 255) & ~(size_t)255;
        return p;
    };
    int*      deg      = (int*)     alloc((size_t)NN * 4);
    float*    dis      = (float*)   alloc((size_t)NN * 4);
    int*      rowstart = (int*)     alloc((size_t)NN * 4);
    int*      bcount   = (int*)     alloc((size_t)NBUK * 4);   // } one memset span
    float*    acc      = (float*)   alloc((size_t)D * 4);      // } (bcount..acc)
    unsigned int* binned = (unsigned int*)alloc((size_t)NBUK * CAP * 4);  // 6.4 MB
    int*      scols    = (int*)     alloc((size_t)NE * 4);
    ushort_t* tPN      = (ushort_t*)alloc((size_t)NN * 128 * 2);   // layer-1 fp16 table (UNSCALED), 25.6 MB
    ushort_t* tPN2     = (ushort_t*)alloc((size_t)NN * 128 * 2);   // layer-2 fp16 table (scaled), 25.6 MB
    uint4*    wfrag    = (uint4*)   alloc((size_t)1024 * 16);      // W2 bf16 hi/lo frags, 16 KB
    // ~65 MB total

    // one memset covers bcount (incl. alignment pad) + acc
    hipMemsetAsync(bcount, 0, (size_t)((char*)acc - (char*)bcount) + (size_t)D * 4, stream);

    // fused preprocessing + layer-1 GEMM (bin blocks + W2-frag block + gemm blocks)
    pre_k<<<NTILES + 1 + G1B, 512, 0, stream>>>(erows, ecols, bcount, binned, NE,
                                                W1, W2, wfrag, x, perm, tPN);
    bucket_sort_k<<<NBUK, 512, 0, stream>>>(binned, bcount, scols, rowstart, deg, dis);

    // fused layer-1 aggregate (per-neighbor dis fmaf, +b1, PReLU) + layer-2 GEMM
    agg_gemm_k<<<NN / 16, 256, 0, stream>>>(tPN, tPN2, dis, rowstart, deg, scols,
                                            b1, prelu_a, wfrag);

    // final aggregate (+b2) -> outputs
    agg_dual_k<<<(NN + 3) / 4, 256, 0, stream>>>(tPN2, outP, outN, dis, rowstart, deg,
                                                 scols, b2, NN);

    // summary = sigmoid(mean(positive, axis=0))
    summary_partial_k<<<512, 256, 0, stream>>>(outP, acc, NN);
    summary_final_k<<<1, 64, 0, stream>>>(acc, outS, NN);
}

// Round 13
// 232.456 us; speedup vs baseline: 1.0957x; 1.0379x over previous
//
#include <hip/hip_runtime.h>
#include <hip/hip_fp16.h>
#include <math.h>

namespace {

constexpr int NN = 100000;   // nodes
constexpr int NE = 1000000;  // edges
constexpr int D  = 64;       // feature dim

constexpr int RPB_LOG = 8;                        // rows per bucket = 256
constexpr int RPB = 1 << RPB_LOG;
constexpr int NBUK = (NN + RPB - 1) >> RPB_LOG;   // 391 buckets
constexpr int CAP = 4096;                         // bucket capacity (mean 2558, +30 sigma)
constexpr int TILE = 8192;                        // edges per bin tile
constexpr int NTILES = (NE + TILE - 1) / TILE;    // 123
constexpr int EPT = TILE / 512;                   // 16 edges per thread
constexpr int G1B = (NN / 16 + 7) / 8;            // gemm1 blocks (8 waves x 16 rows)
constexpr int SUMS = 256;                         // summary spread slots

using ushort_t = unsigned short;
typedef __attribute__((ext_vector_type(8))) short short8;  // 8 bf16 (4 VGPRs)
typedef __attribute__((ext_vector_type(4))) float f32x4;   // MFMA 16x16 accumulator

union FragU { uint4 v; short8 s; };

// split two fp32 into packed bf16 hi parts and packed bf16 lo (residual) parts.
__device__ inline void split2(float f0, float f1, unsigned int& hi, unsigned int& lo) {
    unsigned int u0 = __float_as_uint(f0);
    unsigned int u1 = __float_as_uint(f1);
    hi = (u0 >> 16) | (u1 & 0xffff0000u);
    float l0 = f0 - __uint_as_float(u0 & 0xffff0000u);
    float l1 = f1 - __uint_as_float(u1 & 0xffff0000u);
    lo = (__float_as_uint(l0) >> 16) | (__float_as_uint(l1) & 0xffff0000u);
}

__device__ inline unsigned int packh(float a, float b) {   // 2x fp16 (RNE) packed
    union { __half2 h; unsigned int u; } cv;
    cv.h = __float22half2_rn(make_float2(a, b));
    return cv.u;
}

__device__ inline float2 h2f(unsigned int v) {
    union { unsigned int u; __half2 h; } cv;
    cv.u = v;
    return __half22float2(cv.h);
}

// Build this wave's W^T MFMA A-fragments (bf16 hi/lo) directly from W (L2-hot
// 16KB): lane l holds A[m][k], m = ft*16 + (l&15), k = kt*32 + (l>>4)*8 + j.
__device__ inline void build_wfrags(const float* __restrict__ W, int lane,
                                    FragU (&whi)[4][2], FragU (&wlo)[4][2]) {
#pragma unroll
    for (int ft = 0; ft < 4; ++ft) {
#pragma unroll
        for (int kt = 0; kt < 2; ++kt) {
            int m  = ft * 16 + (lane & 15);
            int k0 = kt * 32 + (lane >> 4) * 8;
            unsigned int hi0, lo0, hi1, lo1, hi2, lo2, hi3, lo3;
            split2(W[(k0 + 0) * 64 + m], W[(k0 + 1) * 64 + m], hi0, lo0);
            split2(W[(k0 + 2) * 64 + m], W[(k0 + 3) * 64 + m], hi1, lo1);
            split2(W[(k0 + 4) * 64 + m], W[(k0 + 5) * 64 + m], hi2, lo2);
            split2(W[(k0 + 6) * 64 + m], W[(k0 + 7) * 64 + m], hi3, lo3);
            whi[ft][kt].v = make_uint4(hi0, hi1, hi2, hi3);
            wlo[ft][kt].v = make_uint4(lo0, lo1, lo2, lo3);
        }
    }
}

// FUSED preprocessing + layer-1 GEMM (independent block roles, co-resident so
// gemm1's compute fills the issue slots the latency/atomic-bound binning
// leaves idle). 512-thread blocks.
// Blocks [0, NTILES): bin 8192 edges each into 391 fixed-capacity row-range
//   buckets. SINGLE LDS atomic per edge (R13): l = atomicAdd(lofs[bk]) is the
//   local index; gbase allocated from the totals; payload written at gbase+l.
//   ONE global allocator atomic per (block,bucket). (R7 lesson: edge-scale
//   device atomics / random 4B stores = ~70us/pass, never again.)
//   Payload packed: (r & 255) << 17 | c.
// Blocks >= NTILES: layer-1 MFMA GEMM, 8 waves x 16 rows per block:
//   tPN[c] = [fp16(x[c]@W1) | fp16(x[perm[c]]@W1)]  -- UNSCALED (dis not yet
//   available; applied per-neighbor at gather time as fmaf with wave-uniform
//   scalar). W1 frags built in-wave (no cross-block dependency).
__global__ void pre_k(const int* __restrict__ rows, const int* __restrict__ cols,
                      int* __restrict__ bcount, unsigned int* __restrict__ binned, int e,
                      const float* __restrict__ W1,
                      const float* __restrict__ x, const int* __restrict__ perm,
                      ushort_t* __restrict__ tPN) {
    __shared__ int gbase[NBUK];
    __shared__ int lofs[NBUK];
    int bid = blockIdx.x;

    if (bid >= NTILES) {
        // ---- layer-1 GEMM path ----
        int lane  = threadIdx.x & 63;
        int wtile = (bid - NTILES) * 8 + (threadIdx.x >> 6);
        if (wtile * 16 >= NN) return;
        int node = wtile * 16 + (lane & 15);
        int kg   = lane >> 4;

        FragU whi[4][2];
        FragU wlo[4][2];
        build_wfrags(W1, lane, whi, wlo);

        const float4* xr = (const float4*)x;
        size_t rbase = (size_t)node * 16 + (size_t)(kg * 2);
        int pnode = perm[node];
        size_t pbase = (size_t)pnode * 16 + (size_t)(kg * 2);
        f32x4 accP[4];
        f32x4 accN[4];
#pragma unroll
        for (int ft = 0; ft < 4; ++ft) {
            accP[ft] = f32x4{0.f, 0.f, 0.f, 0.f};
            accN[ft] = f32x4{0.f, 0.f, 0.f, 0.f};
        }
#pragma unroll
        for (int kt = 0; kt < 2; ++kt) {
            float4 a0 = xr[rbase + kt * 8];
            float4 a1 = xr[rbase + kt * 8 + 1];
            float4 g0 = xr[pbase + kt * 8];
            float4 g1 = xr[pbase + kt * 8 + 1];
            unsigned int h0, l0, h1, l1, h2, l2, h3, l3;
            split2(a0.x, a0.y, h0, l0);
            split2(a0.z, a0.w, h1, l1);
            split2(a1.x, a1.y, h2, l2);
            split2(a1.z, a1.w, h3, l3);
            FragU xhiP, xloP;
            xhiP.v = make_uint4(h0, h1, h2, h3);
            xloP.v = make_uint4(l0, l1, l2, l3);
            split2(g0.x, g0.y, h0, l0);
            split2(g0.z, g0.w, h1, l1);
            split2(g1.x, g1.y, h2, l2);
            split2(g1.z, g1.w, h3, l3);
            FragU xhiN, xloN;
            xhiN.v = make_uint4(h0, h1, h2, h3);
            xloN.v = make_uint4(l0, l1, l2, l3);
#pragma unroll
            for (int ft = 0; ft < 4; ++ft) {
                accP[ft] = __builtin_amdgcn_mfma_f32_16x16x32_bf16(whi[ft][kt].s, xhiP.s, accP[ft], 0, 0, 0);
                accP[ft] = __builtin_amdgcn_mfma_f32_16x16x32_bf16(whi[ft][kt].s, xloP.s, accP[ft], 0, 0, 0);
                accP[ft] = __builtin_amdgcn_mfma_f32_16x16x32_bf16(wlo[ft][kt].s, xhiP.s, accP[ft], 0, 0, 0);
                accN[ft] = __builtin_amdgcn_mfma_f32_16x16x32_bf16(whi[ft][kt].s, xhiN.s, accN[ft], 0, 0, 0);
                accN[ft] = __builtin_amdgcn_mfma_f32_16x16x32_bf16(whi[ft][kt].s, xloN.s, accN[ft], 0, 0, 0);
                accN[ft] = __builtin_amdgcn_mfma_f32_16x16x32_bf16(wlo[ft][kt].s, xhiN.s, accN[ft], 0, 0, 0);
            }
        }
        int fo = kg * 4;
        ushort_t* p = tPN + (size_t)node * 128;
#pragma unroll
        for (int ft = 0; ft < 4; ++ft) {
            uint2 up = make_uint2(packh(accP[ft][0], accP[ft][1]),
                                  packh(accP[ft][2], accP[ft][3]));
            *(uint2*)(p + ft * 16 + fo) = up;
            uint2 un = make_uint2(packh(accN[ft][0], accN[ft][1]),
                                  packh(accN[ft][2], accN[ft][3]));
            *(uint2*)(p + 64 + ft * 16 + fo) = un;
        }
        return;
    }

    // ---- edge binning path (512 thr, 16 edges/thread, 1 LDS atomic/edge) ----
    int base = bid * TILE;
    for (int i = threadIdx.x; i < NBUK; i += blockDim.x) {
        lofs[i] = 0;
    }
    __syncthreads();
    unsigned int v[EPT];
    int bk[EPT];
    int lx[EPT];
#pragma unroll
    for (int j = 0; j < EPT; ++j) {
        int i = base + j * 512 + (int)threadIdx.x;
        if (i < e) {
            int r = rows[i];
            int c = cols[i];
            bk[j] = r >> RPB_LOG;
            v[j] = ((unsigned int)(r & (RPB - 1)) << 17) | (unsigned int)c;
            lx[j] = atomicAdd(&lofs[bk[j]], 1);
        } else {
            bk[j] = -1;
        }
    }
    __syncthreads();
    for (int b = threadIdx.x; b < NBUK; b += blockDim.x) {
        int h = lofs[b];
        gbase[b] = h ? atomicAdd(&bcount[b], h) : 0;
    }
    __syncthreads();
#pragma unroll
    for (int j = 0; j < EPT; ++j) {
        if (bk[j] >= 0) {
            int p = gbase[bk[j]] + lx[j];
            if (p < CAP) {
                binned[(size_t)bk[j] * CAP + p] = v[j];
            }
        }
    }
}

// Phase B: per-bucket counting sort + per-row deg/rowstart/dis production.
// Bucket base (exclusive scan of bcount over buckets < b) computed in-block.
__global__ void bucket_sort_k(const unsigned int* __restrict__ binned,
                              const int* __restrict__ bcount,
                              int* __restrict__ scols, int* __restrict__ rowstart,
                              int* __restrict__ deg, float* __restrict__ dis) {
    __shared__ int lcur[RPB];
    __shared__ int srs[RPB];
    __shared__ int wsum[8];
    __shared__ int redpart[8];
    __shared__ int sbase;
    int b = blockIdx.x;
    int row0 = b << RPB_LOG;
    int nrows = min(RPB, NN - row0);
    int cnt = bcount[b];
    const unsigned int* src = binned + (size_t)b * CAP;
    int tid = threadIdx.x;
    int lane = tid & 63;
    int wid = tid >> 6;

    // in-block exclusive bucket base: sum of bcount[i] for i < b
    int bv = (tid < NBUK && tid < b) ? bcount[tid] : 0;
    int bs = bv;
#pragma unroll
    for (int off = 1; off < 64; off <<= 1) {
        bs += __shfl_xor(bs, off, 64);
    }
    if (lane == 0) redpart[wid] = bs;
    __syncthreads();
    if (tid == 0) {
        int t = 0;
        for (int w = 0; w < 8; ++w) t += redpart[w];
        sbase = t;
    }
    if (tid < RPB) {
        lcur[tid] = 0;
    }
    __syncthreads();
    int bb = sbase;

    for (int i = tid; i < cnt; i += blockDim.x) {
        atomicAdd(&lcur[src[i] >> 17], 1);
    }
    __syncthreads();
    int d = (tid < nrows) ? lcur[tid] : 0;
    int inc = d;
#pragma unroll
    for (int off = 1; off < 64; off <<= 1) {
        int t = __shfl_up(inc, off);
        if (lane >= off) inc += t;
    }
    if (lane == 63) wsum[wid] = inc;
    __syncthreads();
    int wpre = 0;
    for (int w = 0; w < wid; ++w) wpre += wsum[w];
    int gstart = bb + wpre + inc - d;   // global exclusive prefix
    if (tid < nrows) {
        rowstart[row0 + tid] = gstart;
        deg[row0 + tid] = d;
        dis[row0 + tid] = rsqrtf((float)(d + 1));  // +1 self-loop
    }
    __syncthreads();
    if (tid < RPB) {
        srs[tid] = gstart;
        lcur[tid] = 0;
    }
    __syncthreads();
    for (int i = tid; i < cnt; i += blockDim.x) {
        unsigned int v = src[i];
        int rl = (int)(v >> 17);
        int pos = srs[rl] + atomicAdd(&lcur[rl], 1);
        scols[pos] = (int)(v & 0x1FFFFu);
    }
}

// FUSED layer-1 aggregate + layer-2 GEMM. One block (4 waves) owns 16 rows.
// Phase 1 (gather, R2-proven structure): each wave aggregates 4 rows
// sequentially; table is UNSCALED, so each neighbor contributes
// dis[c] * t[c] via fmaf with a wave-uniform scalar dis[c]. Self term
// scaled by dis[r]. H row (post bias+PReLU) parked in LDS [half][16][68].
// Phase 2 (MFMA): waves 0,1 -> P, waves 2,3 -> N; 2 ftiles/wave; W2 frags
// built in-wave from L2-hot W2 (R13: no wfrag buffer/ordering dependency);
// epilogue scales by dis[row], writes SCALED fp16 table tOut (8B stores).
__global__ void agg_gemm_k(const ushort_t* __restrict__ tIn, ushort_t* __restrict__ tOut,
                           const float* __restrict__ dis,
                           const int* __restrict__ rowstart, const int* __restrict__ deg,
                           const int* __restrict__ scols,
                           const float* __restrict__ bias, const float* __restrict__ prelu_a,
                           const float* __restrict__ W2) {
    __shared__ float Hs[2][16][68];
    int tid = threadIdx.x;
    int lane = tid & 63;
    int wv = tid >> 6;                 // 0..3
    int row0 = blockIdx.x * 16;
    int hl = lane & 31;
    int half = lane >> 5;
    size_t lofs = (size_t)(half * 64 + hl * 2);
    float aPr = *prelu_a;

    for (int rr = 0; rr < 4; ++rr) {
        int r = row0 + wv * 4 + rr;
        int rs   = __builtin_amdgcn_readfirstlane(r);
        int base = __builtin_amdgcn_readfirstlane(rowstart[rs]);
        int dg   = __builtin_amdgcn_readfirstlane(deg[rs]);
        float dr = dis[rs];
        unsigned int sv = *(const unsigned int*)(tIn + (size_t)rs * 128 + lofs);
        float2 fs = h2f(sv);
        float a0 = dr * fs.x;
        float a1 = dr * fs.y;     // self-loop term (dis[rs] * t[rs])
        int j = 0;
        for (; j + 4 <= dg; j += 4) {
            int c0 = scols[base + j];
            int c1 = scols[base + j + 1];
            int c2 = scols[base + j + 2];
            int c3 = scols[base + j + 3];
            float d0 = dis[c0];
            float d1 = dis[c1];
            float d2 = dis[c2];
            float d3 = dis[c3];
            unsigned int v0 = *(const unsigned int*)(tIn + (size_t)c0 * 128 + lofs);
            unsigned int v1 = *(const unsigned int*)(tIn + (size_t)c1 * 128 + lofs);
            unsigned int v2 = *(const unsigned int*)(tIn + (size_t)c2 * 128 + lofs);
            unsigned int v3 = *(const unsigned int*)(tIn + (size_t)c3 * 128 + lofs);
            float2 f0 = h2f(v0);
            float2 f1 = h2f(v1);
            float2 f2 = h2f(v2);
            float2 f3 = h2f(v3);
            a0 = fmaf(d0, f0.x, a0);
            a1 = fmaf(d0, f0.y, a1);
            a0 = fmaf(d1, f1.x, a0);
            a1 = fmaf(d1, f1.y, a1);
            a0 = fmaf(d2, f2.x, a0);
            a1 = fmaf(d2, f2.y, a1);
            a0 = fmaf(d3, f3.x, a0);
            a1 = fmaf(d3, f3.y, a1);
        }
        for (; j < dg; ++j) {
            int c = scols[base + j];
            float dc = dis[c];
            unsigned int v = *(const unsigned int*)(tIn + (size_t)c * 128 + lofs);
            float2 f = h2f(v);
            a0 = fmaf(dc, f.x, a0);
            a1 = fmaf(dc, f.y, a1);
        }
        float2 bv = *(const float2*)(bias + 2 * hl);
        float v0 = fmaf(dr, a0, bv.x);
        float v1 = fmaf(dr, a1, bv.y);
        v0 = v0 >= 0.f ? v0 : aPr * v0;
        v1 = v1 >= 0.f ? v1 : aPr * v1;
        int rl = wv * 4 + rr;
        Hs[half][rl][2 * hl]     = v0;
        Hs[half][rl][2 * hl + 1] = v1;
    }
    __syncthreads();

    // layer-2: out[row] = dis[row] * (H[row] @ W2), per half
    int kg = lane >> 4;
    int nd = lane & 15;
    int hsel = wv >> 1;                // waves 0,1 -> P; 2,3 -> N
    int ftb = (wv & 1) * 2;            // ftiles {0,1} or {2,3}
    FragU whi[2][2];
    FragU wlo[2][2];
#pragma unroll
    for (int f2 = 0; f2 < 2; ++f2) {
#pragma unroll
        for (int kt = 0; kt < 2; ++kt) {
            int m  = (ftb + f2) * 16 + (lane & 15);
            int k0 = kt * 32 + (lane >> 4) * 8;
            unsigned int hi0, lo0, hi1, lo1, hi2, lo2, hi3, lo3;
            split2(W2[(k0 + 0) * 64 + m], W2[(k0 + 1) * 64 + m], hi0, lo0);
            split2(W2[(k0 + 2) * 64 + m], W2[(k0 + 3) * 64 + m], hi1, lo1);
            split2(W2[(k0 + 4) * 64 + m], W2[(k0 + 5) * 64 + m], hi2, lo2);
            split2(W2[(k0 + 6) * 64 + m], W2[(k0 + 7) * 64 + m], hi3, lo3);
            whi[f2][kt].v = make_uint4(hi0, hi1, hi2, hi3);
            wlo[f2][kt].v = make_uint4(lo0, lo1, lo2, lo3);
        }
    }
    f32x4 acc[2];
    acc[0] = f32x4{0.f, 0.f, 0.f, 0.f};
    acc[1] = f32x4{0.f, 0.f, 0.f, 0.f};
#pragma unroll
    for (int kt = 0; kt < 2; ++kt) {
        float4 a0 = *(const float4*)&Hs[hsel][nd][kt * 32 + kg * 8];
        float4 a1 = *(const float4*)&Hs[hsel][nd][kt * 32 + kg * 8 + 4];
        unsigned int h0, l0, h1, l1, h2, l2, h3, l3;
        split2(a0.x, a0.y, h0, l0);
        split2(a0.z, a0.w, h1, l1);
        split2(a1.x, a1.y, h2, l2);
        split2(a1.z, a1.w, h3, l3);
        FragU xhi, xlo;
        xhi.v = make_uint4(h0, h1, h2, h3);
        xlo.v = make_uint4(l0, l1, l2, l3);
#pragma unroll
        for (int f2 = 0; f2 < 2; ++f2) {
            acc[f2] = __builtin_amdgcn_mfma_f32_16x16x32_bf16(whi[f2][kt].s, xhi.s, acc[f2], 0, 0, 0);
            acc[f2] = __builtin_amdgcn_mfma_f32_16x16x32_bf16(whi[f2][kt].s, xlo.s, acc[f2], 0, 0, 0);
            acc[f2] = __builtin_amdgcn_mfma_f32_16x16x32_bf16(wlo[f2][kt].s, xhi.s, acc[f2], 0, 0, 0);
        }
    }
    float s = dis[row0 + nd];
    ushort_t* p = tOut + (size_t)(row0 + nd) * 128 + hsel * 64;
    int fo = kg * 4;
#pragma unroll
    for (int f2 = 0; f2 < 2; ++f2) {
        uint2 u = make_uint2(packh(s * acc[f2][0], s * acc[f2][1]),
                             packh(s * acc[f2][2], s * acc[f2][3]));
        *(uint2*)(p + (ftb + f2) * 16 + fo) = u;
    }
}

// Dual gather-aggregate over the interleaved SCALED fp16 table (final layer)
// WITH fused summary partial. One wave per row; lanes 0-31 = P half,
// 32-63 = N half; 2 feats/lane. outX[r] = dis[r]*(sum + self) + b.
// Summary: per-block LDS reduce of the P-half outputs -> one 64-lane
// atomicAdd per block into a 256-slot spread accumulator (R9 lesson:
// same-line atomics serialize at the cross-XCD far point; spreading over
// 256 slots keeps it ~2us total).
__global__ void agg_dual_k(const ushort_t* __restrict__ tPN,
                           float* __restrict__ dstP, float* __restrict__ dstN,
                           const float* __restrict__ dis,
                           const int* __restrict__ rowstart, const int* __restrict__ deg,
                           const int* __restrict__ scols,
                           const float* __restrict__ bias,
                           float* __restrict__ acc2, int n) {
    __shared__ float red[4][64];
    int lane = threadIdx.x & 63;
    int hl = lane & 31;
    int half = lane >> 5;
    int wv = threadIdx.x >> 6;
    int r = blockIdx.x * (blockDim.x >> 6) + wv;
    float v0 = 0.f;
    float v1 = 0.f;
    if (r < n) {
        int rs   = __builtin_amdgcn_readfirstlane(r);
        int base = __builtin_amdgcn_readfirstlane(rowstart[rs]);
        int dg   = __builtin_amdgcn_readfirstlane(deg[rs]);
        float dr = dis[rs];
        size_t lofs = (size_t)(half * 64 + hl * 2);
        unsigned int sv = *(const unsigned int*)(tPN + (size_t)rs * 128 + lofs);
        float2 fs = h2f(sv);
        float a0 = fs.x;
        float a1 = fs.y;     // self-loop term
        int j = 0;
        for (; j + 4 <= dg; j += 4) {
            int c0 = scols[base + j];
            int c1 = scols[base + j + 1];
            int c2 = scols[base + j + 2];
            int c3 = scols[base + j + 3];
            unsigned int u0 = *(const unsigned int*)(tPN + (size_t)c0 * 128 + lofs);
            unsigned int u1 = *(const unsigned int*)(tPN + (size_t)c1 * 128 + lofs);
            unsigned int u2 = *(const unsigned int*)(tPN + (size_t)c2 * 128 + lofs);
            unsigned int u3 = *(const unsigned int*)(tPN + (size_t)c3 * 128 + lofs);
            float2 f0 = h2f(u0);
            float2 f1 = h2f(u1);
            float2 f2 = h2f(u2);
            float2 f3 = h2f(u3);
            a0 += f0.x + f1.x + f2.x + f3.x;
            a1 += f0.y + f1.y + f2.y + f3.y;
        }
        for (; j < dg; ++j) {
            int c = scols[base + j];
            unsigned int u = *(const unsigned int*)(tPN + (size_t)c * 128 + lofs);
            float2 f = h2f(u);
            a0 += f.x;
            a1 += f.y;
        }
        float2 bv = *(const float2*)(bias + 2 * hl);
        v0 = fmaf(dr, a0, bv.x);
        v1 = fmaf(dr, a1, bv.y);
        float* dst = half ? dstN : dstP;
        *(float2*)(dst + (size_t)rs * D + 2 * hl) = float2{v0, v1};
    }
    // summary partial over P-half (half == 0) outputs
    if (half == 0) {
        red[wv][2 * hl]     = v0;
        red[wv][2 * hl + 1] = v1;
    }
    __syncthreads();
    if (threadIdx.x < 64) {
        float t = (red[0][threadIdx.x] + red[1][threadIdx.x]) +
                  (red[2][threadIdx.x] + red[3][threadIdx.x]);
        atomicAdd(&acc2[((blockIdx.x & (SUMS - 1)) << 6) + threadIdx.x], t);
    }
}

// final: reduce the 256 spread slots (constant-trip unrolled -> 64 loads in
// flight per group; R8 lesson: variable-trip `s += load` loops serialize)
__global__ void summary_final_k(const float* __restrict__ acc2, float* __restrict__ out, int n) {
    __shared__ float red[4][64];
    int f = threadIdx.x & 63;
    int g = threadIdx.x >> 6;
    float t = 0.f;
#pragma unroll
    for (int k = 0; k < SUMS / 4; ++k) {
        t += acc2[((g + 4 * k) << 6) + f];
    }
    red[g][f] = t;
    __syncthreads();
    if (threadIdx.x < 64) {
        float m = (red[0][f] + red[1][f] + red[2][f] + red[3][f]) / (float)n;
        out[f] = 1.f / (1.f + expf(-m));
    }
}

} // namespace

extern "C" void kernel_launch(void* const* d_in, const int* in_sizes, int n_in,
                              void* d_out, int out_size, void* d_ws, size_t ws_size,
                              hipStream_t stream) {
    (void)in_sizes; (void)n_in; (void)out_size; (void)ws_size;
    const float* x       = (const float*)d_in[0];
    const int*   ei      = (const int*)  d_in[1];
    const int*   perm    = (const int*)  d_in[2];
    const float* W1      = (const float*)d_in[3];
    const float* b1      = (const float*)d_in[4];
    const float* prelu_a = (const float*)d_in[5];
    const float* W2      = (const float*)d_in[6];
    const float* b2      = (const float*)d_in[7];

    float* outP = (float*)d_out;
    float* outN = outP + (size_t)NN * D;
    float* outS = outN + (size_t)NN * D;

    const int* erows = ei;
    const int* ecols = ei + NE;

    char* ws = (char*)d_ws;
    size_t off = 0;
    auto alloc = [&](size_t bytes) {
        void* p = ws + off;
        off = (off + bytes + 255) & ~(size_t)255;
        return p;
    };
    int*      deg      = (int*)     alloc((size_t)NN * 4);
    float*    dis      = (float*)   alloc((size_t)NN * 4);
    int*      rowstart = (int*)     alloc((size_t)NN * 4);
    int*      bcount   = (int*)     alloc((size_t)NBUK * 4);       // } one memset span
    float*    acc2     = (float*)   alloc((size_t)SUMS * D * 4);   // } (bcount..acc2), 64KB
    unsigned int* binned = (unsigned int*)alloc((size_t)NBUK * CAP * 4);  // 6.4 MB
    int*      scols    = (int*)     alloc((size_t)NE * 4);
    ushort_t* tPN      = (ushort_t*)alloc((size_t)NN * 128 * 2);   // layer-1 fp16 table (UNSCALED), 25.6 MB
    ushort_t* tPN2     = (ushort_t*)alloc((size_t)NN * 128 * 2);   // layer-2 fp16 table (scaled), 25.6 MB
    // ~65 MB total

    // one memset covers bcount (incl. alignment pad) + acc2
    hipMemsetAsync(bcount, 0,
                   (size_t)((char*)acc2 - (char*)bcount) + (size_t)SUMS * D * 4, stream);

    // fused preprocessing + layer-1 GEMM (bin blocks + gemm blocks)
    pre_k<<<NTILES + G1B, 512, 0, stream>>>(erows, ecols, bcount, binned, NE,
                                            W1, x, perm, tPN);
    bucket_sort_k<<<NBUK, 512, 0, stream>>>(binned, bcount, scols, rowstart, deg, dis);

    // fused layer-1 aggregate (per-neighbor dis fmaf, +b1, PReLU) + layer-2 GEMM
    agg_gemm_k<<<NN / 16, 256, 0, stream>>>(tPN, tPN2, dis, rowstart, deg, scols,
                                            b1, prelu_a, W2);

    // final aggregate (+b2) + fused summary partial -> outputs + spread acc
    agg_dual_k<<<(NN + 3) / 4, 256, 0, stream>>>(tPN2, outP, outN, dis, rowstart, deg,
                                                 scols, b2, acc2, NN);

    // summary = sigmoid(mean(positive, axis=0))
    summary_final_k<<<1, 256, 0, stream>>>(acc2, outS, NN);
}

// Round 14
// 225.840 us; speedup vs baseline: 1.1278x; 1.0293x over previous
//
#include <hip/hip_runtime.h>
#include <hip/hip_fp16.h>
#include <math.h>

namespace {

constexpr int NN = 100000;   // nodes
constexpr int NE = 1000000;  // edges
constexpr int D  = 64;       // feature dim

constexpr int RPB_LOG = 8;                        // rows per bucket = 256
constexpr int RPB = 1 << RPB_LOG;
constexpr int NBUK = (NN + RPB - 1) >> RPB_LOG;   // 391 buckets
constexpr int CAP = 4096;                         // bucket capacity (mean 2558, +30 sigma)
constexpr int TILE = 8192;                        // edges per bin tile
constexpr int NTILES = (NE + TILE - 1) / TILE;    // 123
constexpr int EPT = TILE / 512;                   // 16 edges per thread
constexpr int G1B = (NN / 16 + 7) / 8;            // gemm1 blocks (8 waves x 16 rows)
constexpr int SUMS = 256;                         // summary spread slots

using ushort_t = unsigned short;
typedef __attribute__((ext_vector_type(8))) short short8;  // 8 bf16 (4 VGPRs)
typedef __attribute__((ext_vector_type(4))) float f32x4;   // MFMA 16x16 accumulator

union FragU { uint4 v; short8 s; };

// split two fp32 into packed bf16 hi parts and packed bf16 lo (residual) parts.
__device__ inline void split2(float f0, float f1, unsigned int& hi, unsigned int& lo) {
    unsigned int u0 = __float_as_uint(f0);
    unsigned int u1 = __float_as_uint(f1);
    hi = (u0 >> 16) | (u1 & 0xffff0000u);
    float l0 = f0 - __uint_as_float(u0 & 0xffff0000u);
    float l1 = f1 - __uint_as_float(u1 & 0xffff0000u);
    lo = (__float_as_uint(l0) >> 16) | (__float_as_uint(l1) & 0xffff0000u);
}

__device__ inline unsigned int packh(float a, float b) {   // 2x fp16 (RNE) packed
    union { __half2 h; unsigned int u; } cv;
    cv.h = __float22half2_rn(make_float2(a, b));
    return cv.u;
}

__device__ inline float2 h2f(unsigned int v) {
    union { unsigned int u; __half2 h; } cv;
    cv.u = v;
    return __half22float2(cv.h);
}

// Build this wave's W^T MFMA A-fragments (bf16 hi/lo) directly from W (L2-hot
// 16KB): lane l holds A[m][k], m = ft*16 + (l&15), k = kt*32 + (l>>4)*8 + j.
__device__ inline void build_wfrags(const float* __restrict__ W, int lane,
                                    FragU (&whi)[4][2], FragU (&wlo)[4][2]) {
#pragma unroll
    for (int ft = 0; ft < 4; ++ft) {
#pragma unroll
        for (int kt = 0; kt < 2; ++kt) {
            int m  = ft * 16 + (lane & 15);
            int k0 = kt * 32 + (lane >> 4) * 8;
            unsigned int hi0, lo0, hi1, lo1, hi2, lo2, hi3, lo3;
            split2(W[(k0 + 0) * 64 + m], W[(k0 + 1) * 64 + m], hi0, lo0);
            split2(W[(k0 + 2) * 64 + m], W[(k0 + 3) * 64 + m], hi1, lo1);
            split2(W[(k0 + 4) * 64 + m], W[(k0 + 5) * 64 + m], hi2, lo2);
            split2(W[(k0 + 6) * 64 + m], W[(k0 + 7) * 64 + m], hi3, lo3);
            whi[ft][kt].v = make_uint4(hi0, hi1, hi2, hi3);
            wlo[ft][kt].v = make_uint4(lo0, lo1, lo2, lo3);
        }
    }
}

// FUSED preprocessing + layer-1 GEMM (independent block roles, co-resident so
// gemm1's compute fills the issue slots the latency/atomic-bound binning
// leaves idle). 512-thread blocks.
// Blocks [0, NTILES): bin 8192 edges each into 391 fixed-capacity row-range
//   buckets. SINGLE LDS atomic per edge: l = atomicAdd(lofs[bk]) is the local
//   index; gbase allocated from totals; payload written at gbase+l. ONE global
//   allocator atomic per (block,bucket). (R7 lesson: edge-scale device atomics
//   / random 4B stores = ~70us/pass, never again.)
// Block NTILES: W2 MFMA A-fragments -> fb (R14: reverted to precomputed table;
//   R13's per-block in-wave build cost +2us VALU on agg_gemm).
// Blocks > NTILES: layer-1 MFMA GEMM, 8 waves x 16 rows per block:
//   tPN[c] = [fp16(x[c]@W1) | fp16(x[perm[c]]@W1)]  -- UNSCALED (dis applied
//   per-neighbor at gather time). W1 frags built in-wave.
__global__ void pre_k(const int* __restrict__ rows, const int* __restrict__ cols,
                      int* __restrict__ bcount, unsigned int* __restrict__ binned, int e,
                      const float* __restrict__ W1, const float* __restrict__ W2,
                      uint4* __restrict__ fb,
                      const float* __restrict__ x, const int* __restrict__ perm,
                      ushort_t* __restrict__ tPN) {
    __shared__ int gbase[NBUK];
    __shared__ int lofs[NBUK];
    int bid = blockIdx.x;

    if (bid > NTILES) {
        // ---- layer-1 GEMM path ----
        int lane  = threadIdx.x & 63;
        int wtile = (bid - NTILES - 1) * 8 + (threadIdx.x >> 6);
        if (wtile * 16 >= NN) return;
        int node = wtile * 16 + (lane & 15);
        int kg   = lane >> 4;

        FragU whi[4][2];
        FragU wlo[4][2];
        build_wfrags(W1, lane, whi, wlo);

        const float4* xr = (const float4*)x;
        size_t rbase = (size_t)node * 16 + (size_t)(kg * 2);
        int pnode = perm[node];
        size_t pbase = (size_t)pnode * 16 + (size_t)(kg * 2);
        f32x4 accP[4];
        f32x4 accN[4];
#pragma unroll
        for (int ft = 0; ft < 4; ++ft) {
            accP[ft] = f32x4{0.f, 0.f, 0.f, 0.f};
            accN[ft] = f32x4{0.f, 0.f, 0.f, 0.f};
        }
#pragma unroll
        for (int kt = 0; kt < 2; ++kt) {
            float4 a0 = xr[rbase + kt * 8];
            float4 a1 = xr[rbase + kt * 8 + 1];
            float4 g0 = xr[pbase + kt * 8];
            float4 g1 = xr[pbase + kt * 8 + 1];
            unsigned int h0, l0, h1, l1, h2, l2, h3, l3;
            split2(a0.x, a0.y, h0, l0);
            split2(a0.z, a0.w, h1, l1);
            split2(a1.x, a1.y, h2, l2);
            split2(a1.z, a1.w, h3, l3);
            FragU xhiP, xloP;
            xhiP.v = make_uint4(h0, h1, h2, h3);
            xloP.v = make_uint4(l0, l1, l2, l3);
            split2(g0.x, g0.y, h0, l0);
            split2(g0.z, g0.w, h1, l1);
            split2(g1.x, g1.y, h2, l2);
            split2(g1.z, g1.w, h3, l3);
            FragU xhiN, xloN;
            xhiN.v = make_uint4(h0, h1, h2, h3);
            xloN.v = make_uint4(l0, l1, l2, l3);
#pragma unroll
            for (int ft = 0; ft < 4; ++ft) {
                accP[ft] = __builtin_amdgcn_mfma_f32_16x16x32_bf16(whi[ft][kt].s, xhiP.s, accP[ft], 0, 0, 0);
                accP[ft] = __builtin_amdgcn_mfma_f32_16x16x32_bf16(whi[ft][kt].s, xloP.s, accP[ft], 0, 0, 0);
                accP[ft] = __builtin_amdgcn_mfma_f32_16x16x32_bf16(wlo[ft][kt].s, xhiP.s, accP[ft], 0, 0, 0);
                accN[ft] = __builtin_amdgcn_mfma_f32_16x16x32_bf16(whi[ft][kt].s, xhiN.s, accN[ft], 0, 0, 0);
                accN[ft] = __builtin_amdgcn_mfma_f32_16x16x32_bf16(whi[ft][kt].s, xloN.s, accN[ft], 0, 0, 0);
                accN[ft] = __builtin_amdgcn_mfma_f32_16x16x32_bf16(wlo[ft][kt].s, xhiN.s, accN[ft], 0, 0, 0);
            }
        }
        int fo = kg * 4;
        ushort_t* p = tPN + (size_t)node * 128;
#pragma unroll
        for (int ft = 0; ft < 4; ++ft) {
            uint2 up = make_uint2(packh(accP[ft][0], accP[ft][1]),
                                  packh(accP[ft][2], accP[ft][3]));
            *(uint2*)(p + ft * 16 + fo) = up;
            uint2 un = make_uint2(packh(accN[ft][0], accN[ft][1]),
                                  packh(accN[ft][2], accN[ft][3]));
            *(uint2*)(p + 64 + ft * 16 + fo) = un;
        }
        return;
    }

    if (bid == NTILES) {
        // ---- W2 fragment table for agg_gemm ----
        int lane = threadIdx.x;
        if (lane < 64) {
            for (int ft = 0; ft < 4; ++ft) {
                for (int kt = 0; kt < 2; ++kt) {
                    int m  = ft * 16 + (lane & 15);
                    int k0 = kt * 32 + (lane >> 4) * 8;
                    unsigned int hi0, lo0, hi1, lo1, hi2, lo2, hi3, lo3;
                    split2(W2[(k0 + 0) * 64 + m], W2[(k0 + 1) * 64 + m], hi0, lo0);
                    split2(W2[(k0 + 2) * 64 + m], W2[(k0 + 3) * 64 + m], hi1, lo1);
                    split2(W2[(k0 + 4) * 64 + m], W2[(k0 + 5) * 64 + m], hi2, lo2);
                    split2(W2[(k0 + 6) * 64 + m], W2[(k0 + 7) * 64 + m], hi3, lo3);
                    fb[((ft * 2 + kt) * 2 + 0) * 64 + lane] = make_uint4(hi0, hi1, hi2, hi3);
                    fb[((ft * 2 + kt) * 2 + 1) * 64 + lane] = make_uint4(lo0, lo1, lo2, lo3);
                }
            }
        }
        return;
    }

    // ---- edge binning path (512 thr, 16 edges/thread, 1 LDS atomic/edge) ----
    int base = bid * TILE;
    for (int i = threadIdx.x; i < NBUK; i += blockDim.x) {
        lofs[i] = 0;
    }
    __syncthreads();
    unsigned int v[EPT];
    int bk[EPT];
    int lx[EPT];
#pragma unroll
    for (int j = 0; j < EPT; ++j) {
        int i = base + j * 512 + (int)threadIdx.x;
        if (i < e) {
            int r = rows[i];
            int c = cols[i];
            bk[j] = r >> RPB_LOG;
            v[j] = ((unsigned int)(r & (RPB - 1)) << 17) | (unsigned int)c;
            lx[j] = atomicAdd(&lofs[bk[j]], 1);
        } else {
            bk[j] = -1;
        }
    }
    __syncthreads();
    for (int b = threadIdx.x; b < NBUK; b += blockDim.x) {
        int h = lofs[b];
        gbase[b] = h ? atomicAdd(&bcount[b], h) : 0;
    }
    __syncthreads();
#pragma unroll
    for (int j = 0; j < EPT; ++j) {
        if (bk[j] >= 0) {
            int p = gbase[bk[j]] + lx[j];
            if (p < CAP) {
                binned[(size_t)bk[j] * CAP + p] = v[j];
            }
        }
    }
}

// Phase B: per-bucket counting sort + per-row deg/rowstart/dis production.
// Bucket base (exclusive scan of bcount over buckets < b) computed in-block.
__global__ void bucket_sort_k(const unsigned int* __restrict__ binned,
                              const int* __restrict__ bcount,
                              int* __restrict__ scols, int* __restrict__ rowstart,
                              int* __restrict__ deg, float* __restrict__ dis) {
    __shared__ int lcur[RPB];
    __shared__ int srs[RPB];
    __shared__ int wsum[8];
    __shared__ int redpart[8];
    __shared__ int sbase;
    int b = blockIdx.x;
    int row0 = b << RPB_LOG;
    int nrows = min(RPB, NN - row0);
    int cnt = bcount[b];
    const unsigned int* src = binned + (size_t)b * CAP;
    int tid = threadIdx.x;
    int lane = tid & 63;
    int wid = tid >> 6;

    // in-block exclusive bucket base: sum of bcount[i] for i < b
    int bv = (tid < NBUK && tid < b) ? bcount[tid] : 0;
    int bs = bv;
#pragma unroll
    for (int off = 1; off < 64; off <<= 1) {
        bs += __shfl_xor(bs, off, 64);
    }
    if (lane == 0) redpart[wid] = bs;
    __syncthreads();
    if (tid == 0) {
        int t = 0;
        for (int w = 0; w < 8; ++w) t += redpart[w];
        sbase = t;
    }
    if (tid < RPB) {
        lcur[tid] = 0;
    }
    __syncthreads();
    int bb = sbase;

    for (int i = tid; i < cnt; i += blockDim.x) {
        atomicAdd(&lcur[src[i] >> 17], 1);
    }
    __syncthreads();
    int d = (tid < nrows) ? lcur[tid] : 0;
    int inc = d;
#pragma unroll
    for (int off = 1; off < 64; off <<= 1) {
        int t = __shfl_up(inc, off);
        if (lane >= off) inc += t;
    }
    if (lane == 63) wsum[wid] = inc;
    __syncthreads();
    int wpre = 0;
    for (int w = 0; w < wid; ++w) wpre += wsum[w];
    int gstart = bb + wpre + inc - d;   // global exclusive prefix
    if (tid < nrows) {
        rowstart[row0 + tid] = gstart;
        deg[row0 + tid] = d;
        dis[row0 + tid] = rsqrtf((float)(d + 1));  // +1 self-loop
    }
    __syncthreads();
    if (tid < RPB) {
        srs[tid] = gstart;
        lcur[tid] = 0;
    }
    __syncthreads();
    for (int i = tid; i < cnt; i += blockDim.x) {
        unsigned int v = src[i];
        int rl = (int)(v >> 17);
        int pos = srs[rl] + atomicAdd(&lcur[rl], 1);
        scols[pos] = (int)(v & 0x1FFFFu);
    }
}

// FUSED layer-1 aggregate + layer-2 GEMM. One block (4 waves) owns 16 rows.
// Phase 1 (gather): each wave aggregates 4 rows sequentially; UNSCALED table,
// per-neighbor dis[c] fmaf (wave-uniform scalar). R14: serial tail replaced by
// ONE PREDICATED 4-deep batch (OOB slots -> c=rs L2-hot, weight 0): latency
// rounds per mean-deg-10 row drop 4 -> 3. scols stays wave-uniform scalar
// (R3/R4 lessons). H row (post bias+PReLU) parked in LDS [half][16][68].
// Phase 2 (MFMA): waves 0,1 -> P, waves 2,3 -> N; W2 frags from precomputed
// table; epilogue scales by dis[row], writes SCALED fp16 table tOut.
__global__ void agg_gemm_k(const ushort_t* __restrict__ tIn, ushort_t* __restrict__ tOut,
                           const float* __restrict__ dis,
                           const int* __restrict__ rowstart, const int* __restrict__ deg,
                           const int* __restrict__ scols,
                           const float* __restrict__ bias, const float* __restrict__ prelu_a,
                           const uint4* __restrict__ wf) {
    __shared__ float Hs[2][16][68];
    int tid = threadIdx.x;
    int lane = tid & 63;
    int wv = tid >> 6;                 // 0..3
    int row0 = blockIdx.x * 16;
    int hl = lane & 31;
    int half = lane >> 5;
    size_t lofs = (size_t)(half * 64 + hl * 2);
    float aPr = *prelu_a;

    for (int rr = 0; rr < 4; ++rr) {
        int r = row0 + wv * 4 + rr;
        int rs   = __builtin_amdgcn_readfirstlane(r);
        int base = __builtin_amdgcn_readfirstlane(rowstart[rs]);
        int dg   = __builtin_amdgcn_readfirstlane(deg[rs]);
        float dr = dis[rs];
        unsigned int sv = *(const unsigned int*)(tIn + (size_t)rs * 128 + lofs);
        float2 fs = h2f(sv);
        float a0 = dr * fs.x;
        float a1 = dr * fs.y;     // self-loop term (dis[rs] * t[rs])
        int j = 0;
        for (; j + 4 <= dg; j += 4) {
            int c0 = scols[base + j];
            int c1 = scols[base + j + 1];
            int c2 = scols[base + j + 2];
            int c3 = scols[base + j + 3];
            float d0 = dis[c0];
            float d1 = dis[c1];
            float d2 = dis[c2];
            float d3 = dis[c3];
            unsigned int v0 = *(const unsigned int*)(tIn + (size_t)c0 * 128 + lofs);
            unsigned int v1 = *(const unsigned int*)(tIn + (size_t)c1 * 128 + lofs);
            unsigned int v2 = *(const unsigned int*)(tIn + (size_t)c2 * 128 + lofs);
            unsigned int v3 = *(const unsigned int*)(tIn + (size_t)c3 * 128 + lofs);
            float2 f0 = h2f(v0);
            float2 f1 = h2f(v1);
            float2 f2 = h2f(v2);
            float2 f3 = h2f(v3);
            a0 = fmaf(d0, f0.x, a0);
            a1 = fmaf(d0, f0.y, a1);
            a0 = fmaf(d1, f1.x, a0);
            a1 = fmaf(d1, f1.y, a1);
            a0 = fmaf(d2, f2.x, a0);
            a1 = fmaf(d2, f2.y, a1);
            a0 = fmaf(d3, f3.x, a0);
            a1 = fmaf(d3, f3.y, a1);
        }
        if (j < dg) {               // predicated tail batch, full 4-deep ILP
            int c0 = scols[base + j];
            int c1 = (j + 1 < dg) ? scols[base + j + 1] : rs;
            int c2 = (j + 2 < dg) ? scols[base + j + 2] : rs;
            int c3 = (j + 3 < dg) ? scols[base + j + 3] : rs;
            float d0 = dis[c0];
            float d1 = (j + 1 < dg) ? dis[c1] : 0.f;
            float d2 = (j + 2 < dg) ? dis[c2] : 0.f;
            float d3 = (j + 3 < dg) ? dis[c3] : 0.f;
            unsigned int v0 = *(const unsigned int*)(tIn + (size_t)c0 * 128 + lofs);
            unsigned int v1 = *(const unsigned int*)(tIn + (size_t)c1 * 128 + lofs);
            unsigned int v2 = *(const unsigned int*)(tIn + (size_t)c2 * 128 + lofs);
            unsigned int v3 = *(const unsigned int*)(tIn + (size_t)c3 * 128 + lofs);
            float2 f0 = h2f(v0);
            float2 f1 = h2f(v1);
            float2 f2 = h2f(v2);
            float2 f3 = h2f(v3);
            a0 = fmaf(d0, f0.x, a0);
            a1 = fmaf(d0, f0.y, a1);
            a0 = fmaf(d1, f1.x, a0);
            a1 = fmaf(d1, f1.y, a1);
            a0 = fmaf(d2, f2.x, a0);
            a1 = fmaf(d2, f2.y, a1);
            a0 = fmaf(d3, f3.x, a0);
            a1 = fmaf(d3, f3.y, a1);
        }
        float2 bv = *(const float2*)(bias + 2 * hl);
        float v0 = fmaf(dr, a0, bv.x);
        float v1 = fmaf(dr, a1, bv.y);
        v0 = v0 >= 0.f ? v0 : aPr * v0;
        v1 = v1 >= 0.f ? v1 : aPr * v1;
        int rl = wv * 4 + rr;
        Hs[half][rl][2 * hl]     = v0;
        Hs[half][rl][2 * hl + 1] = v1;
    }
    __syncthreads();

    // layer-2: out[row] = dis[row] * (H[row] @ W2), per half
    int kg = lane >> 4;
    int nd = lane & 15;
    int hsel = wv >> 1;                // waves 0,1 -> P; 2,3 -> N
    int ftb = (wv & 1) * 2;            // ftiles {0,1} or {2,3}
    FragU whi[2][2];
    FragU wlo[2][2];
#pragma unroll
    for (int f2 = 0; f2 < 2; ++f2) {
#pragma unroll
        for (int kt = 0; kt < 2; ++kt) {
            whi[f2][kt].v = wf[(((ftb + f2) * 2 + kt) * 2 + 0) * 64 + lane];
            wlo[f2][kt].v = wf[(((ftb + f2) * 2 + kt) * 2 + 1) * 64 + lane];
        }
    }
    f32x4 acc[2];
    acc[0] = f32x4{0.f, 0.f, 0.f, 0.f};
    acc[1] = f32x4{0.f, 0.f, 0.f, 0.f};
#pragma unroll
    for (int kt = 0; kt < 2; ++kt) {
        float4 a0 = *(const float4*)&Hs[hsel][nd][kt * 32 + kg * 8];
        float4 a1 = *(const float4*)&Hs[hsel][nd][kt * 32 + kg * 8 + 4];
        unsigned int h0, l0, h1, l1, h2, l2, h3, l3;
        split2(a0.x, a0.y, h0, l0);
        split2(a0.z, a0.w, h1, l1);
        split2(a1.x, a1.y, h2, l2);
        split2(a1.z, a1.w, h3, l3);
        FragU xhi, xlo;
        xhi.v = make_uint4(h0, h1, h2, h3);
        xlo.v = make_uint4(l0, l1, l2, l3);
#pragma unroll
        for (int f2 = 0; f2 < 2; ++f2) {
            acc[f2] = __builtin_amdgcn_mfma_f32_16x16x32_bf16(whi[f2][kt].s, xhi.s, acc[f2], 0, 0, 0);
            acc[f2] = __builtin_amdgcn_mfma_f32_16x16x32_bf16(whi[f2][kt].s, xlo.s, acc[f2], 0, 0, 0);
            acc[f2] = __builtin_amdgcn_mfma_f32_16x16x32_bf16(wlo[f2][kt].s, xhi.s, acc[f2], 0, 0, 0);
        }
    }
    float s = dis[row0 + nd];
    ushort_t* p = tOut + (size_t)(row0 + nd) * 128 + hsel * 64;
    int fo = kg * 4;
#pragma unroll
    for (int f2 = 0; f2 < 2; ++f2) {
        uint2 u = make_uint2(packh(s * acc[f2][0], s * acc[f2][1]),
                             packh(s * acc[f2][2], s * acc[f2][3]));
        *(uint2*)(p + (ftb + f2) * 16 + fo) = u;
    }
}

// Dual gather-aggregate over the interleaved SCALED fp16 table (final layer)
// WITH fused summary partial. One wave per row; lanes 0-31 = P half,
// 32-63 = N half; 2 feats/lane. R14: predicated tail batch (weight 1/0,
// OOB -> c=rs), no serial tail. Summary: per-block LDS reduce -> one 64-lane
// atomicAdd per block into a 256-slot spread accumulator (R9 lesson).
__global__ void agg_dual_k(const ushort_t* __restrict__ tPN,
                           float* __restrict__ dstP, float* __restrict__ dstN,
                           const float* __restrict__ dis,
                           const int* __restrict__ rowstart, const int* __restrict__ deg,
                           const int* __restrict__ scols,
                           const float* __restrict__ bias,
                           float* __restrict__ acc2, int n) {
    __shared__ float red[4][64];
    int lane = threadIdx.x & 63;
    int hl = lane & 31;
    int half = lane >> 5;
    int wv = threadIdx.x >> 6;
    int r = blockIdx.x * (blockDim.x >> 6) + wv;
    float v0 = 0.f;
    float v1 = 0.f;
    if (r < n) {
        int rs   = __builtin_amdgcn_readfirstlane(r);
        int base = __builtin_amdgcn_readfirstlane(rowstart[rs]);
        int dg   = __builtin_amdgcn_readfirstlane(deg[rs]);
        float dr = dis[rs];
        size_t lofs = (size_t)(half * 64 + hl * 2);
        unsigned int sv = *(const unsigned int*)(tPN + (size_t)rs * 128 + lofs);
        float2 fs = h2f(sv);
        float a0 = fs.x;
        float a1 = fs.y;     // self-loop term
        int j = 0;
        for (; j + 4 <= dg; j += 4) {
            int c0 = scols[base + j];
            int c1 = scols[base + j + 1];
            int c2 = scols[base + j + 2];
            int c3 = scols[base + j + 3];
            unsigned int u0 = *(const unsigned int*)(tPN + (size_t)c0 * 128 + lofs);
            unsigned int u1 = *(const unsigned int*)(tPN + (size_t)c1 * 128 + lofs);
            unsigned int u2 = *(const unsigned int*)(tPN + (size_t)c2 * 128 + lofs);
            unsigned int u3 = *(const unsigned int*)(tPN + (size_t)c3 * 128 + lofs);
            float2 f0 = h2f(u0);
            float2 f1 = h2f(u1);
            float2 f2 = h2f(u2);
            float2 f3 = h2f(u3);
            a0 += f0.x + f1.x + f2.x + f3.x;
            a1 += f0.y + f1.y + f2.y + f3.y;
        }
        if (j < dg) {               // predicated tail batch, full 4-deep ILP
            int c0 = scols[base + j];
            int c1 = (j + 1 < dg) ? scols[base + j + 1] : rs;
            int c2 = (j + 2 < dg) ? scols[base + j + 2] : rs;
            int c3 = (j + 3 < dg) ? scols[base + j + 3] : rs;
            float w1 = (j + 1 < dg) ? 1.f : 0.f;
            float w2 = (j + 2 < dg) ? 1.f : 0.f;
            float w3 = (j + 3 < dg) ? 1.f : 0.f;
            unsigned int u0 = *(const unsigned int*)(tPN + (size_t)c0 * 128 + lofs);
            unsigned int u1 = *(const unsigned int*)(tPN + (size_t)c1 * 128 + lofs);
            unsigned int u2 = *(const unsigned int*)(tPN + (size_t)c2 * 128 + lofs);
            unsigned int u3 = *(const unsigned int*)(tPN + (size_t)c3 * 128 + lofs);
            float2 f0 = h2f(u0);
            float2 f1 = h2f(u1);
            float2 f2 = h2f(u2);
            float2 f3 = h2f(u3);
            a0 += f0.x;
            a1 += f0.y;
            a0 = fmaf(w1, f1.x, a0);
            a1 = fmaf(w1, f1.y, a1);
            a0 = fmaf(w2, f2.x, a0);
            a1 = fmaf(w2, f2.y, a1);
            a0 = fmaf(w3, f3.x, a0);
            a1 = fmaf(w3, f3.y, a1);
        }
        float2 bv = *(const float2*)(bias + 2 * hl);
        v0 = fmaf(dr, a0, bv.x);
        v1 = fmaf(dr, a1, bv.y);
        float* dst = half ? dstN : dstP;
        *(float2*)(dst + (size_t)rs * D + 2 * hl) = float2{v0, v1};
    }
    // summary partial over P-half (half == 0) outputs
    if (half == 0) {
        red[wv][2 * hl]     = v0;
        red[wv][2 * hl + 1] = v1;
    }
    __syncthreads();
    if (threadIdx.x < 64) {
        float t = (red[0][threadIdx.x] + red[1][threadIdx.x]) +
                  (red[2][threadIdx.x] + red[3][threadIdx.x]);
        atomicAdd(&acc2[((blockIdx.x & (SUMS - 1)) << 6) + threadIdx.x], t);
    }
}

// final: reduce the 256 spread slots (constant-trip unrolled -> 64 loads in
// flight per group; R8 lesson: variable-trip `s += load` loops serialize)
__global__ void summary_final_k(const float* __restrict__ acc2, float* __restrict__ out, int n) {
    __shared__ float red[4][64];
    int f = threadIdx.x & 63;
    int g = threadIdx.x >> 6;
    float t = 0.f;
#pragma unroll
    for (int k = 0; k < SUMS / 4; ++k) {
        t += acc2[((g + 4 * k) << 6) + f];
    }
    red[g][f] = t;
    __syncthreads();
    if (threadIdx.x < 64) {
        float m = (red[0][f] + red[1][f] + red[2][f] + red[3][f]) / (float)n;
        out[f] = 1.f / (1.f + expf(-m));
    }
}

} // namespace

extern "C" void kernel_launch(void* const* d_in, const int* in_sizes, int n_in,
                              void* d_out, int out_size, void* d_ws, size_t ws_size,
                              hipStream_t stream) {
    (void)in_sizes; (void)n_in; (void)out_size; (void)ws_size;
    const float* x       = (const float*)d_in[0];
    const int*   ei      = (const int*)  d_in[1];
    const int*   perm    = (const int*)  d_in[2];
    const float* W1      = (const float*)d_in[3];
    const float* b1      = (const float*)d_in[4];
    const float* prelu_a = (const float*)d_in[5];
    const float* W2      = (const float*)d_in[6];
    const float* b2      = (const float*)d_in[7];

    float* outP = (float*)d_out;
    float* outN = outP + (size_t)NN * D;
    float* outS = outN + (size_t)NN * D;

    const int* erows = ei;
    const int* ecols = ei + NE;

    char* ws = (char*)d_ws;
    size_t off = 0;
    auto alloc = [&](size_t bytes) {
        void* p = ws + off;
        off = (off + bytes + 255) & ~(size_t)255;
        return p;
    };
    int*      deg      = (int*)     alloc((size_t)NN * 4);
    float*    dis      = (float*)   alloc((size_t)NN * 4);
    int*      rowstart = (int*)     alloc((size_t)NN * 4);
    int*      bcount   = (int*)     alloc((size_t)NBUK * 4);       // } one memset span
    float*    acc2     = (float*)   alloc((size_t)SUMS * D * 4);   // } (bcount..acc2), 64KB
    unsigned int* binned = (unsigned int*)alloc((size_t)NBUK * CAP * 4);  // 6.4 MB
    int*      scols    = (int*)     alloc((size_t)NE * 4);
    ushort_t* tPN      = (ushort_t*)alloc((size_t)NN * 128 * 2);   // layer-1 fp16 table (UNSCALED), 25.6 MB
    ushort_t* tPN2     = (ushort_t*)alloc((size_t)NN * 128 * 2);   // layer-2 fp16 table (scaled), 25.6 MB
    uint4*    wfrag    = (uint4*)   alloc((size_t)1024 * 16);      // W2 bf16 hi/lo frags, 16 KB
    // ~65 MB total

    // one memset covers bcount (incl. alignment pad) + acc2
    hipMemsetAsync(bcount, 0,
                   (size_t)((char*)acc2 - (char*)bcount) + (size_t)SUMS * D * 4, stream);

    // fused preprocessing + layer-1 GEMM (bin blocks + W2-frag block + gemm blocks)
    pre_k<<<NTILES + 1 + G1B, 512, 0, stream>>>(erows, ecols, bcount, binned, NE,
                                                W1, W2, wfrag, x, perm, tPN);
    bucket_sort_k<<<NBUK, 512, 0, stream>>>(binned, bcount, scols, rowstart, deg, dis);

    // fused layer-1 aggregate (per-neighbor dis fmaf, +b1, PReLU) + layer-2 GEMM
    agg_gemm_k<<<NN / 16, 256, 0, stream>>>(tPN, tPN2, dis, rowstart, deg, scols,
                                            b1, prelu_a, wfrag);

    // final aggregate (+b2) + fused summary partial -> outputs + spread acc
    agg_dual_k<<<(NN + 3) / 4, 256, 0, stream>>>(tPN2, outP, outN, dis, rowstart, deg,
                                                 scols, b2, acc2, NN);

    // summary = sigmoid(mean(positive, axis=0))
    summary_final_k<<<1, 256, 0, stream>>>(acc2, outS, NN);
}